// Round 12
// baseline (404.537 us; speedup 1.0000x reference)
//
#include <hip/hip_runtime.h>
#include <hip/hip_bf16.h>

// SOLD2 line matching on MI355X.
// Inputs: line_seg1 (1200,2,2) f32, line_seg2 (1200,2,2) f32,
//         desc1 (1,128,128,128) f32, desc2 (1,128,128,128) f32
// Outputs (concat float32): matches (1200,), nw (1200,20)

#define NLINES 1200
#define NS 5
#define DD 128
#define HH 128
#define WW 128
#define HW (HH*WW)
#define IMGM1 511.0f
#define GAPC 0.1f
#define NPAD 1216          // 38*32
#define PPAD (NPAD*NS)     // 6080 padded points
#define KEXT 384           // 3-term bf16 split: [hi,lo,hi] x [hi,hi,lo]
#define NCH (KEXT/32)      // 12 k-chunks of 32
#define NGRP (PPAD/16)     // 380 16-pt groups

typedef __attribute__((ext_vector_type(8))) short short8;
typedef __attribute__((ext_vector_type(4))) float f32x4;

__device__ __forceinline__ void async_cp16(const void* g, void* l) {
    __builtin_amdgcn_global_load_lds(
        (const __attribute__((address_space(1))) void*)g,
        (__attribute__((address_space(3))) void*)l, 16, 0, 0);
}

// ------ K0: transpose desc [D][H][W] -> [H*W][D], float4 both ways --------
__global__ void transpose_desc(const float* __restrict__ in1, float* __restrict__ out1,
                               const float* __restrict__ in2, float* __restrict__ out2) {
    const float* in = blockIdx.z ? in2 : in1;
    float* out = blockIdx.z ? out2 : out1;
    __shared__ float t[32][132];
    int s0 = blockIdx.x * 128;         // HW dim
    int d0 = blockIdx.y * 32;          // D dim
    int tid = threadIdx.x;
    #pragma unroll
    for (int pass = 0; pass < 4; ++pass) {
        int idx = pass * 256 + tid;    // 0..1023 = 32 d x 32 s-chunks
        int dr = idx >> 5, si = idx & 31;
        float4 v = *(const float4*)&in[(size_t)(d0 + dr) * HW + s0 + 4 * si];
        *(float4*)&t[dr][4 * si] = v;
    }
    __syncthreads();
    #pragma unroll
    for (int pass = 0; pass < 4; ++pass) {
        int idx = pass * 256 + tid;    // 0..1023 = 128 s x 8 d-chunks
        int sr = idx >> 3, di = idx & 7;
        float4 v = { t[4 * di][sr], t[4 * di + 1][sr], t[4 * di + 2][sr], t[4 * di + 3][sr] };
        *(float4*)&out[(size_t)(s0 + sr) * DD + d0 + 4 * di] = v;
    }
}

// ------- K1: fused sample + bilinear + normalize + bf16 split + pack ------
__global__ void samplepack_kernel(const float* __restrict__ lseg1, const float* __restrict__ lseg2,
                                  const float* __restrict__ tdesc1, const float* __restrict__ tdesc2,
                                  const float* __restrict__ desc1, const float* __restrict__ desc2,
                                  short* __restrict__ Aext, short* __restrict__ Bext,
                                  float* __restrict__ val1, float* __restrict__ val2,
                                  int use_t) {
    int side = blockIdx.y;
    const float* lseg = side ? lseg2 : lseg1;
    const float* tdesc = side ? tdesc2 : tdesc1;
    const float* desc = side ? desc2 : desc1;
    short* Ef = side ? Bext : Aext;
    float* valout = side ? val2 : val1;
    int arole = side ? 0 : 1;          // A: [hi,lo,hi]; B: [hi,hi,lo]

    __shared__ float ds[16][129];
    int g = blockIdx.x;
    int t = threadIdx.x;
    int lane = t & 63, w = t >> 6;

    #pragma unroll
    for (int s = 0; s < 4; ++s) {
        int r = w * 4 + s;
        int pt = g * 16 + r;
        int line = pt / NS;
        int k = pt - line * NS;

        float sy = 0.f, sx = 0.f, ey = 0.f, ex = 0.f;
        if (line < NLINES) {
            sy = lseg[line * 4 + 0]; sx = lseg[line * 4 + 1];
            ey = lseg[line * 4 + 2]; ex = lseg[line * 4 + 3];
        }
        float dy = ey - sy, dx = ex - sx;
        float len = sqrtf(dy * dy + dx * dx);
        float ns = floorf(len * 0.125f);
        ns = fminf(fmaxf(ns, 2.0f), 5.0f);
        float kf = (float)k;
        float validf = (kf < ns) ? 1.0f : 0.0f;
        float py = sy + kf * (dy / (ns - 1.0f));
        float px = sx + kf * (dx / (ns - 1.0f));
        if (validf == 0.0f) { py = 0.0f; px = 0.0f; }

        float xn = 2.0f * px / IMGM1 - 1.0f;
        float yn = 2.0f * py / IMGM1 - 1.0f;
        float ix = ((xn + 1.0f) * (float)WW - 1.0f) * 0.5f;
        float iy = ((yn + 1.0f) * (float)HH - 1.0f) * 0.5f;
        float x0f = floorf(ix), y0f = floorf(iy);
        float wx = ix - x0f, wy = iy - y0f;
        int x0 = (int)x0f, y0 = (int)y0f;

        float w00 = (1.0f - wx) * (1.0f - wy);
        float w10 = wx * (1.0f - wy);
        float w01 = (1.0f - wx) * wy;
        float w11 = wx * wy;

        float v0 = 0.0f, v1 = 0.0f;
        int xs[4] = { x0, x0 + 1, x0,     x0 + 1 };
        int ys[4] = { y0, y0,     y0 + 1, y0 + 1 };
        float ws4[4] = { w00, w10, w01, w11 };
        #pragma unroll
        for (int c = 0; c < 4; ++c) {
            int xi = xs[c], yi = ys[c];
            float inb = (xi >= 0 && xi < WW && yi >= 0 && yi < HH) ? 1.0f : 0.0f;
            int xc = min(max(xi, 0), WW - 1);
            int yc = min(max(yi, 0), HH - 1);
            if (use_t) {
                int base = (yc * WW + xc) * DD;
                v0 += tdesc[base + lane] * inb * ws4[c];
                v1 += tdesc[base + 64 + lane] * inb * ws4[c];
            } else {
                int base = yc * WW + xc;
                v0 += desc[lane * HW + base] * inb * ws4[c];
                v1 += desc[(lane + 64) * HW + base] * inb * ws4[c];
            }
        }
        float ss = v0 * v0 + v1 * v1;
        #pragma unroll
        for (int o = 32; o > 0; o >>= 1) ss += __shfl_xor(ss, o);
        if (ss == 0.0f) ss = 1.0f;   // padding lines: avoid 0/0 NaN
        float nrm = sqrtf(ss);
        ds[r][lane] = v0 / nrm;
        ds[r][64 + lane] = v1 / nrm;
        if (lane == 0) valout[pt] = (line < NLINES) ? validf : 0.0f;
    }
    __syncthreads();

    #pragma unroll
    for (int it = 0; it < 3; ++it) {
        int idx = it * 256 + t;        // 0..767 = 12 chunks x 64 lanes
        int c = idx >> 6, l = idx & 63;
        int q = l >> 4, r = l & 15;
        short8 outv;
        #pragma unroll
        for (int jj = 0; jj < 8; ++jj) {
            int kext = c * 32 + q * 8 + jj;
            int term = kext >> 7, k = kext & 127;
            float x = ds[r][k];
            __hip_bfloat16 h = __float2bfloat16(x);
            short v = *(short*)&h;
            bool lo_term = arole ? (term == 1) : (term == 2);
            if (lo_term) {
                float hf = __bfloat162float(h);
                __hip_bfloat16 lw = __float2bfloat16(x - hf);
                v = *(short*)&lw;
            }
            outv[jj] = v;
        }
        *(short8*)&Ef[((size_t)(g * NCH + c) * 64 + l) * 8] = outv;
    }
}

// ---------------- K2: MFMA score GEMM + fused per-line-pair reduction -----
// A: register double-buffer direct-global. B: LDS-staged once per block.
// Epilogue in 4 quadrant phases -> 27 KB LDS -> 4 blocks/CU at VGPR<=128:
// the K-loop barrier drains and L2 latency hide behind 3 other blocks.
__launch_bounds__(256, 4)
__global__ void score_kernel(const short* __restrict__ Af, const short* __restrict__ Bf,
                             const float* __restrict__ val1, const float* __restrict__ val2,
                             float* __restrict__ lsc, float* __restrict__ lscT) {
    __shared__ union {
        struct { short B[2][5120]; } st;                        // 20480 B
        struct { float dump[80 * 81]; float red[16][17]; } ep;  // 27008 B
    } u;

    const int t = threadIdx.x;
    const int lane = t & 63;
    const int w = t >> 6;           // wave 0..3
    const int wm = w >> 1;          // 0..1 row half
    const int wn = w & 1;           // 0..1 col half
    const int gA0 = blockIdx.x * 10;   // first 16-pt group of A side
    const int gB0 = blockIdx.y * 10;

    const short* pa[5];
    #pragma unroll
    for (int ti = 0; ti < 5; ++ti)
        pa[ti] = Af + ((size_t)(gA0 + 5 * wm + ti) * NCH * 64 + lane) * 8;

    f32x4 acc[5][5];
    #pragma unroll
    for (int a = 0; a < 5; ++a)
        #pragma unroll
        for (int b = 0; b < 5; ++b)
            acc[a][b] = (f32x4){0.f, 0.f, 0.f, 0.f};

    // stage B chunk c into buffer b: waves 0,1 handle 5 groups each
    auto stageB = [&](int c, int b) {
        if (w < 2) {
            #pragma unroll
            for (int p = 0; p < 5; ++p) {
                int gi = w * 5 + p;
                const short* g = Bf + ((size_t)((gB0 + gi) * NCH + c) * 64 + lane) * 8;
                async_cp16(g, &u.st.B[b][gi * 512]);
            }
        }
    };

    short8 ca[5], na[5];
    stageB(0, 0);
    #pragma unroll
    for (int ti = 0; ti < 5; ++ti) ca[ti] = *(const short8*)(pa[ti]);

    #pragma unroll
    for (int c = 0; c < NCH; ++c) {
        __syncthreads();               // drains stage(c) + A-loads(c); both used now
        if (c + 1 < NCH) {
            stageB(c + 1, (c + 1) & 1);
            #pragma unroll
            for (int ti = 0; ti < 5; ++ti)
                na[ti] = *(const short8*)(pa[ti] + (c + 1) * 512);
        }
        short8 bf_[5];
        #pragma unroll
        for (int tj = 0; tj < 5; ++tj)
            bf_[tj] = *(const short8*)&u.st.B[c & 1][(5 * wn + tj) * 512 + lane * 8];
        #pragma unroll
        for (int ti = 0; ti < 5; ++ti)
            #pragma unroll
            for (int tj = 0; tj < 5; ++tj)
                acc[ti][tj] = __builtin_amdgcn_mfma_f32_16x16x32_bf16(
                    ca[ti], bf_[tj], acc[ti][tj], 0, 0, 0);
        #pragma unroll
        for (int ti = 0; ti < 5; ++ti) ca[ti] = na[ti];
    }

    // epilogue: 4 quadrant phases (wm x wn), 16x16 lines each
    const int i0l = blockIdx.x * 32;
    const int j0l = blockIdx.y * 32;
    const int q2 = lane >> 4, r2 = lane & 15;
    #pragma unroll
    for (int p = 0; p < 2; ++p) {
        #pragma unroll
        for (int pn = 0; pn < 2; ++pn) {
            __syncthreads();
            if (wm == p && wn == pn) {
                #pragma unroll
                for (int ti = 0; ti < 5; ++ti)
                    #pragma unroll
                    for (int reg = 0; reg < 4; ++reg) {
                        int rloc = 16 * ti + q2 * 4 + reg;
                        #pragma unroll
                        for (int tj = 0; tj < 5; ++tj)
                            u.ep.dump[rloc * 81 + 16 * tj + r2] = acc[ti][tj][reg];
                    }
            }
            __syncthreads();
            {
                int li = t >> 4, lj = t & 15;
                int i = i0l + 16 * p + li;
                int j = j0l + 16 * pn + lj;
                float S[5][5];
                #pragma unroll
                for (int a = 0; a < 5; ++a) {
                    float va = val1[i * NS + a];   // i < NPAD always: safe
                    #pragma unroll
                    for (int b = 0; b < 5; ++b) {
                        float vb = val2[j * NS + b];
                        float sc = u.ep.dump[(li * 5 + a) * 81 + (lj * 5 + b)];
                        S[a][b] = (va != 0.0f && vb != 0.0f) ? sc : -1.0f;
                    }
                }
                float sum1 = 0.0f, cnt1 = 0.0f;
                #pragma unroll
                for (int a = 0; a < 5; ++a) {
                    float r = S[a][0];
                    #pragma unroll
                    for (int b = 1; b < 5; ++b) r = fmaxf(r, S[a][b]);
                    float v = (r != -1.0f) ? 1.0f : 0.0f;
                    sum1 += r * v; cnt1 += v;
                }
                float sum2 = 0.0f, cnt2 = 0.0f;
                #pragma unroll
                for (int b = 0; b < 5; ++b) {
                    float r = S[0][b];
                    #pragma unroll
                    for (int a = 1; a < 5; ++a) r = fmaxf(r, S[a][b]);
                    float v = (r != -1.0f) ? 1.0f : 0.0f;
                    sum2 += r * v; cnt2 += v;
                }
                float res = (sum1 / cnt1 + sum2 / cnt2) * 0.5f;
                u.ep.red[li][lj] = res;
                if (i < NLINES && j < NLINES) lsc[i * NLINES + j] = res;
            }
            __syncthreads();
            {
                int lj = t >> 4, li = t & 15;
                int i = i0l + 16 * p + li;
                int j = j0l + 16 * pn + lj;
                if (i < NLINES && j < NLINES) lscT[j * NLINES + i] = u.ep.red[li][lj];
            }
        }
    }
}

// ------- K3: fused per-row top-10 + Needleman-Wunsch (320 thr = 5 waves) --
// Phase 0: all waves stage shared-line fragments to LDS. Phase 1: wave 0
// alone does top-10 in registers (19 vals/lane, wave shuffles only -- zero
// block barriers in the 10-round loop). Phase 2: wave w -> candidates
// 2w,2w+1 via one 12-chunk MFMA chain; 20 lanes run the NW DP.
__device__ __forceinline__ float nw5(const float* M) {
    float F[6] = {0, 0, 0, 0, 0, 0};
    #pragma unroll
    for (int x = 0; x < 5; ++x) {
        float diag = F[0];
        float left = 0.0f;
        #pragma unroll
        for (int y = 1; y <= 5; ++y) {
            float up = F[y];
            float cur = fmaxf(fmaxf(left, up), diag + (M[x * 5 + y - 1] - GAPC));
            F[y] = cur; left = cur; diag = up;
        }
    }
    return F[5];
}

__global__ void topk_nw_kernel(const float* __restrict__ lsc, const float* __restrict__ lscT,
                               const short* __restrict__ Af, const short* __restrict__ Bf,
                               const float* __restrict__ val1, const float* __restrict__ val2,
                               int* __restrict__ topk1, int* __restrict__ topk2,
                               float* __restrict__ nwout, float* __restrict__ nw2buf) {
    __shared__ short sh_lds[NCH * 512];     // 12 KB: shared line fragments
    __shared__ float sbuf[10][25];
    __shared__ int jl[10];
    int rb = blockIdx.x;                    // 0..2399
    int dir = (rb >= NLINES) ? 1 : 0;
    int row = rb - dir * NLINES;
    int t = threadIdx.x;                    // 0..319
    int w = t >> 6;                         // wave 0..4
    int lane = t & 63;
    int q = lane >> 4, rr = lane & 15;

    const short* shEf = dir ? Bf : Af;      // shared side
    const short* cdEf = dir ? Af : Bf;      // candidate side
    const float* ls = dir ? (lscT + (size_t)row * NLINES) : (lsc + (size_t)row * NLINES);
    int* topk = dir ? (topk2 + row * 10) : (topk1 + row * 10);

    // phase 0: stage shared-line fragments (drains during topk)
    for (int idx = t; idx < NCH * 64; idx += 320) {
        int c = idx >> 6, l = idx & 63;
        int lq = l >> 4, lr = l & 15;
        int ptS = row * 5 + min(lr, 4);
        const short* gp = shEf + ((size_t)(ptS >> 4) * NCH * 64 + lq * 16 + (ptS & 15)) * 8
                               + (size_t)c * 512;
        *(short8*)&sh_lds[c * 512 + l * 8] = *(const short8*)gp;
    }

    // phase 1: wave 0 does top-10 alone (stable-argsort ties: larger index)
    if (w == 0) {
        float val[19];
        #pragma unroll
        for (int s = 0; s < 19; ++s) {
            int j = lane + 64 * s;
            val[s] = (j < NLINES) ? ls[j] : -1e30f;
        }
        for (int sel = 0; sel < 10; ++sel) {
            float bv = -1e30f; int bi = -1;
            #pragma unroll
            for (int s = 0; s < 19; ++s) {
                int j = lane + 64 * s;
                if (val[s] >= bv) { bv = val[s]; bi = j; }
            }
            #pragma unroll
            for (int o = 32; o > 0; o >>= 1) {
                float ov = __shfl_xor(bv, o);
                int oi = __shfl_xor(bi, o);
                if (ov > bv || (ov == bv && oi > bi)) { bv = ov; bi = oi; }
            }
            if (lane == 0) { topk[9 - sel] = bi; jl[9 - sel] = bi; }
            if ((bi & 63) == lane) val[bi >> 6] = -1e30f;
        }
    }
    __syncthreads();                        // jl + sh_lds ready

    // phase 2: MFMA scores for 10 candidates (2 per wave) + NW DP
    int c1 = jl[2 * w], c2 = jl[2 * w + 1];
    int ptC = (rr < 8) ? (c1 * 5 + min(rr, 4)) : (c2 * 5 + min(rr - 8, 4));
    const short* cp = cdEf + ((size_t)(ptC >> 4) * NCH * 64 + q * 16 + (ptC & 15)) * 8;

    f32x4 acc = (f32x4){0.f, 0.f, 0.f, 0.f};
    #pragma unroll
    for (int c = 0; c < NCH; ++c) {
        short8 sh = *(const short8*)&sh_lds[c * 512 + lane * 8];
        short8 cb = *(const short8*)(cp + c * 512);
        acc = dir ? __builtin_amdgcn_mfma_f32_16x16x32_bf16(cb, sh, acc, 0, 0, 0)
                  : __builtin_amdgcn_mfma_f32_16x16x32_bf16(sh, cb, acc, 0, 0, 0);
    }
    // C layout: m = q*4+reg, n = lane&15
    #pragma unroll
    for (int reg = 0; reg < 4; ++reg) {
        int m = q * 4 + reg, n = rr;
        if (!dir) {
            if (m < 5 && n < 5) sbuf[2 * w][m * 5 + n] = acc[reg];
            if (m < 5 && n >= 8 && n < 13) sbuf[2 * w + 1][m * 5 + (n - 8)] = acc[reg];
        } else {
            if (m < 5 && n < 5) sbuf[2 * w][m * 5 + n] = acc[reg];
            if (m >= 8 && m < 13 && n < 5) sbuf[2 * w + 1][(m - 8) * 5 + n] = acc[reg];
        }
    }
    __syncthreads();

    if (t < 20) {
        int r = t >> 1, rev = t & 1;
        int i = dir ? jl[r] : row;
        int j = dir ? row : jl[r];
        float S[25];
        #pragma unroll
        for (int a = 0; a < 5; ++a) {
            float va = val1[i * NS + a];
            #pragma unroll
            for (int b = 0; b < 5; ++b) {
                float vb = val2[j * NS + b];
                S[a * 5 + b] = (va != 0.0f && vb != 0.0f) ? sbuf[r][a * 5 + b] : -1.0f;
            }
        }
        float M[25];
        #pragma unroll
        for (int x = 0; x < 5; ++x)
            #pragma unroll
            for (int y = 0; y < 5; ++y) {
                if (!dir) M[x * 5 + y] = rev ? S[x * 5 + (4 - y)] : S[x * 5 + y];
                else      M[x * 5 + y] = rev ? S[(4 - y) * 5 + x] : S[y * 5 + x];
            }
        float nwv = nw5(M);
        float* o = dir ? nw2buf : nwout;
        o[row * 20 + rev * 10 + r] = nwv;
    }
}

// ---------------- K4: argmax over 20 + mutual check (single block) --------
__global__ void argmax_final_kernel(const float* __restrict__ nw1, const float* __restrict__ nw2,
                                    const int* __restrict__ topk1, const int* __restrict__ topk2,
                                    float* __restrict__ out) {
    __shared__ int mpre[NLINES];
    __shared__ int m2[NLINES];
    int t = threadIdx.x;               // 0..1023
    for (int qq = t; qq < 2 * NLINES; qq += 1024) {
        int dir = qq / NLINES, row = qq - dir * NLINES;
        const float* nw = (dir ? nw2 : nw1) + row * 20;
        float best = nw[0]; int bi = 0;
        #pragma unroll
        for (int q = 1; q < 20; ++q) {
            float v = nw[q];
            if (v > best) { best = v; bi = q; }
        }
        int m = (dir ? topk2 : topk1)[row * 10 + (bi % 10)];
        if (dir) m2[row] = m; else mpre[row] = m;
    }
    __syncthreads();
    for (int i = t; i < NLINES; i += 1024) {
        int m = mpre[i];
        out[i] = (m2[m] == i) ? (float)m : -1.0f;
    }
}

extern "C" void kernel_launch(void* const* d_in, const int* in_sizes, int n_in,
                              void* d_out, int out_size, void* d_ws, size_t ws_size,
                              hipStream_t stream) {
    const float* lseg1 = (const float*)d_in[0];
    const float* lseg2 = (const float*)d_in[1];
    const float* desc1 = (const float*)d_in[2];
    const float* desc2 = (const float*)d_in[3];
    float* out = (float*)d_out;

    float* wsf = (float*)d_ws;
    size_t off = 0;
    float* val1 = wsf + off;   off += PPAD;
    float* val2 = wsf + off;   off += PPAD;
    float* lsc = wsf + off;    off += (size_t)NLINES * NLINES;
    float* lscT = wsf + off;   off += (size_t)NLINES * NLINES;
    int* topk1 = (int*)(wsf + off); off += NLINES * 10;
    int* topk2 = (int*)(wsf + off); off += NLINES * 10;
    float* nw2buf = wsf + off; off += NLINES * 20;
    short* Aext = (short*)(wsf + off); off += (size_t)PPAD * KEXT / 2;
    short* Bext = (short*)(wsf + off); off += (size_t)PPAD * KEXT / 2;
    float* tdesc1 = wsf + off; off += (size_t)HW * DD;
    float* tdesc2 = wsf + off; off += (size_t)HW * DD;
    size_t need_full = off * sizeof(float);
    int use_t = (ws_size >= need_full) ? 1 : 0;

    if (use_t) {
        transpose_desc<<<dim3(HW / 128, DD / 32, 2), 256, 0, stream>>>(
            desc1, tdesc1, desc2, tdesc2);
    }
    samplepack_kernel<<<dim3(NGRP, 2), 256, 0, stream>>>(
        lseg1, lseg2, tdesc1, tdesc2, desc1, desc2, Aext, Bext, val1, val2, use_t);

    score_kernel<<<dim3(NPAD / 32, NPAD / 32), 256, 0, stream>>>(Aext, Bext, val1, val2,
                                                                 lsc, lscT);

    topk_nw_kernel<<<2 * NLINES, 320, 0, stream>>>(lsc, lscT, Aext, Bext, val1, val2,
                                                   topk1, topk2, out + NLINES, nw2buf);

    argmax_final_kernel<<<1, 1024, 0, stream>>>(out + NLINES, nw2buf, topk1, topk2, out);
}

// Round 13
// 182.617 us; speedup vs baseline: 2.2152x; 2.2152x over previous
//
#include <hip/hip_runtime.h>
#include <hip/hip_bf16.h>

// SOLD2 line matching on MI355X.
// Inputs: line_seg1 (1200,2,2) f32, line_seg2 (1200,2,2) f32,
//         desc1 (1,128,128,128) f32, desc2 (1,128,128,128) f32
// Outputs (concat float32): matches (1200,), nw (1200,20)

#define NLINES 1200
#define NS 5
#define DD 128
#define HH 128
#define WW 128
#define HW (HH*WW)
#define IMGM1 511.0f
#define GAPC 0.1f
#define NPAD 1216          // 38*32
#define PPAD (NPAD*NS)     // 6080 padded points
#define KEXT 384           // 3-term bf16 split: [hi,lo,hi] x [hi,hi,lo]
#define NCH (KEXT/32)      // 12 k-chunks of 32
#define NGRP (PPAD/16)     // 380 16-pt groups

typedef __attribute__((ext_vector_type(8))) short short8;
typedef __attribute__((ext_vector_type(4))) float f32x4;

__device__ __forceinline__ void async_cp16(const void* g, void* l) {
    __builtin_amdgcn_global_load_lds(
        (const __attribute__((address_space(1))) void*)g,
        (__attribute__((address_space(3))) void*)l, 16, 0, 0);
}

// ------ K0: transpose desc [D][H][W] -> [H*W][D], float4 both ways --------
__global__ void transpose_desc(const float* __restrict__ in1, float* __restrict__ out1,
                               const float* __restrict__ in2, float* __restrict__ out2) {
    const float* in = blockIdx.z ? in2 : in1;
    float* out = blockIdx.z ? out2 : out1;
    __shared__ float t[32][132];
    int s0 = blockIdx.x * 128;         // HW dim
    int d0 = blockIdx.y * 32;          // D dim
    int tid = threadIdx.x;
    #pragma unroll
    for (int pass = 0; pass < 4; ++pass) {
        int idx = pass * 256 + tid;    // 0..1023 = 32 d x 32 s-chunks
        int dr = idx >> 5, si = idx & 31;
        float4 v = *(const float4*)&in[(size_t)(d0 + dr) * HW + s0 + 4 * si];
        *(float4*)&t[dr][4 * si] = v;
    }
    __syncthreads();
    #pragma unroll
    for (int pass = 0; pass < 4; ++pass) {
        int idx = pass * 256 + tid;    // 0..1023 = 128 s x 8 d-chunks
        int sr = idx >> 3, di = idx & 7;
        float4 v = { t[4 * di][sr], t[4 * di + 1][sr], t[4 * di + 2][sr], t[4 * di + 3][sr] };
        *(float4*)&out[(size_t)(s0 + sr) * DD + d0 + 4 * di] = v;
    }
}

// ------- K1: fused sample + bilinear + normalize + bf16 split + pack ------
__global__ void samplepack_kernel(const float* __restrict__ lseg1, const float* __restrict__ lseg2,
                                  const float* __restrict__ tdesc1, const float* __restrict__ tdesc2,
                                  const float* __restrict__ desc1, const float* __restrict__ desc2,
                                  short* __restrict__ Aext, short* __restrict__ Bext,
                                  float* __restrict__ val1, float* __restrict__ val2,
                                  int use_t) {
    int side = blockIdx.y;
    const float* lseg = side ? lseg2 : lseg1;
    const float* tdesc = side ? tdesc2 : tdesc1;
    const float* desc = side ? desc2 : desc1;
    short* Ef = side ? Bext : Aext;
    float* valout = side ? val2 : val1;
    int arole = side ? 0 : 1;          // A: [hi,lo,hi]; B: [hi,hi,lo]

    __shared__ float ds[16][129];
    int g = blockIdx.x;
    int t = threadIdx.x;
    int lane = t & 63, w = t >> 6;

    #pragma unroll
    for (int s = 0; s < 4; ++s) {
        int r = w * 4 + s;
        int pt = g * 16 + r;
        int line = pt / NS;
        int k = pt - line * NS;

        float sy = 0.f, sx = 0.f, ey = 0.f, ex = 0.f;
        if (line < NLINES) {
            sy = lseg[line * 4 + 0]; sx = lseg[line * 4 + 1];
            ey = lseg[line * 4 + 2]; ex = lseg[line * 4 + 3];
        }
        float dy = ey - sy, dx = ex - sx;
        float len = sqrtf(dy * dy + dx * dx);
        float ns = floorf(len * 0.125f);
        ns = fminf(fmaxf(ns, 2.0f), 5.0f);
        float kf = (float)k;
        float validf = (kf < ns) ? 1.0f : 0.0f;
        float py = sy + kf * (dy / (ns - 1.0f));
        float px = sx + kf * (dx / (ns - 1.0f));
        if (validf == 0.0f) { py = 0.0f; px = 0.0f; }

        float xn = 2.0f * px / IMGM1 - 1.0f;
        float yn = 2.0f * py / IMGM1 - 1.0f;
        float ix = ((xn + 1.0f) * (float)WW - 1.0f) * 0.5f;
        float iy = ((yn + 1.0f) * (float)HH - 1.0f) * 0.5f;
        float x0f = floorf(ix), y0f = floorf(iy);
        float wx = ix - x0f, wy = iy - y0f;
        int x0 = (int)x0f, y0 = (int)y0f;

        float w00 = (1.0f - wx) * (1.0f - wy);
        float w10 = wx * (1.0f - wy);
        float w01 = (1.0f - wx) * wy;
        float w11 = wx * wy;

        float v0 = 0.0f, v1 = 0.0f;
        int xs[4] = { x0, x0 + 1, x0,     x0 + 1 };
        int ys[4] = { y0, y0,     y0 + 1, y0 + 1 };
        float ws4[4] = { w00, w10, w01, w11 };
        #pragma unroll
        for (int c = 0; c < 4; ++c) {
            int xi = xs[c], yi = ys[c];
            float inb = (xi >= 0 && xi < WW && yi >= 0 && yi < HH) ? 1.0f : 0.0f;
            int xc = min(max(xi, 0), WW - 1);
            int yc = min(max(yi, 0), HH - 1);
            if (use_t) {
                int base = (yc * WW + xc) * DD;
                v0 += tdesc[base + lane] * inb * ws4[c];
                v1 += tdesc[base + 64 + lane] * inb * ws4[c];
            } else {
                int base = yc * WW + xc;
                v0 += desc[lane * HW + base] * inb * ws4[c];
                v1 += desc[(lane + 64) * HW + base] * inb * ws4[c];
            }
        }
        float ss = v0 * v0 + v1 * v1;
        #pragma unroll
        for (int o = 32; o > 0; o >>= 1) ss += __shfl_xor(ss, o);
        if (ss == 0.0f) ss = 1.0f;   // padding lines: avoid 0/0 NaN
        float nrm = sqrtf(ss);
        ds[r][lane] = v0 / nrm;
        ds[r][64 + lane] = v1 / nrm;
        if (lane == 0) valout[pt] = (line < NLINES) ? validf : 0.0f;
    }
    __syncthreads();

    #pragma unroll
    for (int it = 0; it < 3; ++it) {
        int idx = it * 256 + t;        // 0..767 = 12 chunks x 64 lanes
        int c = idx >> 6, l = idx & 63;
        int q = l >> 4, r = l & 15;
        short8 outv;
        #pragma unroll
        for (int jj = 0; jj < 8; ++jj) {
            int kext = c * 32 + q * 8 + jj;
            int term = kext >> 7, k = kext & 127;
            float x = ds[r][k];
            __hip_bfloat16 h = __float2bfloat16(x);
            short v = *(short*)&h;
            bool lo_term = arole ? (term == 1) : (term == 2);
            if (lo_term) {
                float hf = __bfloat162float(h);
                __hip_bfloat16 lw = __float2bfloat16(x - hf);
                v = *(short*)&lw;
            }
            outv[jj] = v;
        }
        *(short8*)&Ef[((size_t)(g * NCH + c) * 64 + l) * 8] = outv;
    }
}

// ---------------- K2: MFMA score GEMM + fused per-line-pair reduction -----
// R11 proven structure (51.1 us): A register double-buffer direct-global,
// B LDS-staged once per block, bounds(256,2). R12's bounds(256,4) spilled
// the 100-reg accumulator to scratch (583 MB writes, 6x slower) -- this
// tile shape is hard-capped at 2 blocks/CU.
__launch_bounds__(256, 2)
__global__ void score_kernel(const short* __restrict__ Af, const short* __restrict__ Bf,
                             const float* __restrict__ val1, const float* __restrict__ val2,
                             float* __restrict__ lsc, float* __restrict__ lscT) {
    __shared__ union {
        struct { short B[2][5120]; } st;                       // 20480 B
        struct { float dump[80 * 161]; float red[16][33]; } ep; // 53632 B
    } u;

    const int t = threadIdx.x;
    const int lane = t & 63;
    const int w = t >> 6;           // wave 0..3
    const int wm = w >> 1;          // 0..1 row half
    const int wn = w & 1;           // 0..1 col half
    const int gA0 = blockIdx.x * 10;   // first 16-pt group of A side
    const int gB0 = blockIdx.y * 10;

    const short* pa[5];
    #pragma unroll
    for (int ti = 0; ti < 5; ++ti)
        pa[ti] = Af + ((size_t)(gA0 + 5 * wm + ti) * NCH * 64 + lane) * 8;

    f32x4 acc[5][5];
    #pragma unroll
    for (int a = 0; a < 5; ++a)
        #pragma unroll
        for (int b = 0; b < 5; ++b)
            acc[a][b] = (f32x4){0.f, 0.f, 0.f, 0.f};

    // stage B chunk c into buffer b: waves 0,1 handle 5 groups each
    auto stageB = [&](int c, int b) {
        if (w < 2) {
            #pragma unroll
            for (int p = 0; p < 5; ++p) {
                int gi = w * 5 + p;
                const short* g = Bf + ((size_t)((gB0 + gi) * NCH + c) * 64 + lane) * 8;
                async_cp16(g, &u.st.B[b][gi * 512]);
            }
        }
    };

    short8 ca[5], na[5];
    stageB(0, 0);
    #pragma unroll
    for (int ti = 0; ti < 5; ++ti) ca[ti] = *(const short8*)(pa[ti]);

    #pragma unroll
    for (int c = 0; c < NCH; ++c) {
        __syncthreads();               // drains stage(c) + A-loads(c); both used now
        if (c + 1 < NCH) {
            stageB(c + 1, (c + 1) & 1);
            #pragma unroll
            for (int ti = 0; ti < 5; ++ti)
                na[ti] = *(const short8*)(pa[ti] + (c + 1) * 512);
        }
        short8 bf_[5];
        #pragma unroll
        for (int tj = 0; tj < 5; ++tj)
            bf_[tj] = *(const short8*)&u.st.B[c & 1][(5 * wn + tj) * 512 + lane * 8];
        #pragma unroll
        for (int ti = 0; ti < 5; ++ti)
            #pragma unroll
            for (int tj = 0; tj < 5; ++tj)
                acc[ti][tj] = __builtin_amdgcn_mfma_f32_16x16x32_bf16(
                    ca[ti], bf_[tj], acc[ti][tj], 0, 0, 0);
        #pragma unroll
        for (int ti = 0; ti < 5; ++ti) ca[ti] = na[ti];
    }

    const int i0l = blockIdx.x * 32;
    const int j0l = blockIdx.y * 32;
    #pragma unroll
    for (int p = 0; p < 2; ++p) {
        __syncthreads();
        if (wm == p) {
            #pragma unroll
            for (int ti = 0; ti < 5; ++ti) {
                #pragma unroll
                for (int reg = 0; reg < 4; ++reg) {
                    int rloc = 16 * ti + (lane >> 4) * 4 + reg;
                    #pragma unroll
                    for (int tj = 0; tj < 5; ++tj) {
                        int col = 80 * wn + 16 * tj + (lane & 15);
                        u.ep.dump[rloc * 161 + col] = acc[ti][tj][reg];
                    }
                }
            }
        }
        __syncthreads();
        // pass 1: reduce once per pair, write lsc (coalesced in j), park in red
        #pragma unroll
        for (int e = 0; e < 2; ++e) {
            int q = t * 2 + e;            // 0..511
            int li = q >> 5, lj = q & 31;
            int i = i0l + 16 * p + li;
            int j = j0l + lj;
            float S[5][5];
            #pragma unroll
            for (int a = 0; a < 5; ++a) {
                float va = val1[i * NS + a];   // i < NPAD always: safe
                #pragma unroll
                for (int b = 0; b < 5; ++b) {
                    float vb = val2[j * NS + b];
                    float sc = u.ep.dump[(li * 5 + a) * 161 + (lj * 5 + b)];
                    S[a][b] = (va != 0.0f && vb != 0.0f) ? sc : -1.0f;
                }
            }
            float sum1 = 0.0f, cnt1 = 0.0f;
            #pragma unroll
            for (int a = 0; a < 5; ++a) {
                float r = S[a][0];
                #pragma unroll
                for (int b = 1; b < 5; ++b) r = fmaxf(r, S[a][b]);
                float v = (r != -1.0f) ? 1.0f : 0.0f;
                sum1 += r * v; cnt1 += v;
            }
            float sum2 = 0.0f, cnt2 = 0.0f;
            #pragma unroll
            for (int b = 0; b < 5; ++b) {
                float r = S[0][b];
                #pragma unroll
                for (int a = 1; a < 5; ++a) r = fmaxf(r, S[a][b]);
                float v = (r != -1.0f) ? 1.0f : 0.0f;
                sum2 += r * v; cnt2 += v;
            }
            float res = (sum1 / cnt1 + sum2 / cnt2) * 0.5f;
            u.ep.red[li][lj] = res;
            if (i < NLINES && j < NLINES) lsc[i * NLINES + j] = res;
        }
        __syncthreads();
        // pass 2: lscT from red, coalesced in i
        #pragma unroll
        for (int e = 0; e < 2; ++e) {
            int q = t + 256 * e;          // 0..511
            int li = q & 15, lj = q >> 4;
            int i = i0l + 16 * p + li;
            int j = j0l + lj;
            if (i < NLINES && j < NLINES) lscT[j * NLINES + i] = u.ep.red[li][lj];
        }
    }
}

// ------- K3: fused per-row top-10 + Needleman-Wunsch (320 thr = 5 waves) --
// Phase 0: all waves stage shared-line fragments to LDS. Phase 1: wave 0
// alone does top-10 in registers (19 vals/lane, wave shuffles only -- zero
// block barriers in the 10-round loop). Phase 2: wave w -> candidates
// 2w,2w+1 via one 12-chunk MFMA chain; 20 lanes run the NW DP.
__device__ __forceinline__ float nw5(const float* M) {
    float F[6] = {0, 0, 0, 0, 0, 0};
    #pragma unroll
    for (int x = 0; x < 5; ++x) {
        float diag = F[0];
        float left = 0.0f;
        #pragma unroll
        for (int y = 1; y <= 5; ++y) {
            float up = F[y];
            float cur = fmaxf(fmaxf(left, up), diag + (M[x * 5 + y - 1] - GAPC));
            F[y] = cur; left = cur; diag = up;
        }
    }
    return F[5];
}

__global__ void topk_nw_kernel(const float* __restrict__ lsc, const float* __restrict__ lscT,
                               const short* __restrict__ Af, const short* __restrict__ Bf,
                               const float* __restrict__ val1, const float* __restrict__ val2,
                               int* __restrict__ topk1, int* __restrict__ topk2,
                               float* __restrict__ nwout, float* __restrict__ nw2buf) {
    __shared__ short sh_lds[NCH * 512];     // 12 KB: shared line fragments
    __shared__ float sbuf[10][25];
    __shared__ int jl[10];
    int rb = blockIdx.x;                    // 0..2399
    int dir = (rb >= NLINES) ? 1 : 0;
    int row = rb - dir * NLINES;
    int t = threadIdx.x;                    // 0..319
    int w = t >> 6;                         // wave 0..4
    int lane = t & 63;
    int q = lane >> 4, rr = lane & 15;

    const short* shEf = dir ? Bf : Af;      // shared side
    const short* cdEf = dir ? Af : Bf;      // candidate side
    const float* ls = dir ? (lscT + (size_t)row * NLINES) : (lsc + (size_t)row * NLINES);
    int* topk = dir ? (topk2 + row * 10) : (topk1 + row * 10);

    // phase 0: stage shared-line fragments (drains during topk)
    for (int idx = t; idx < NCH * 64; idx += 320) {
        int c = idx >> 6, l = idx & 63;
        int lq = l >> 4, lr = l & 15;
        int ptS = row * 5 + min(lr, 4);
        const short* gp = shEf + ((size_t)(ptS >> 4) * NCH * 64 + lq * 16 + (ptS & 15)) * 8
                               + (size_t)c * 512;
        *(short8*)&sh_lds[c * 512 + l * 8] = *(const short8*)gp;
    }

    // phase 1: wave 0 does top-10 alone (stable-argsort ties: larger index)
    if (w == 0) {
        float val[19];
        #pragma unroll
        for (int s = 0; s < 19; ++s) {
            int j = lane + 64 * s;
            val[s] = (j < NLINES) ? ls[j] : -1e30f;
        }
        for (int sel = 0; sel < 10; ++sel) {
            float bv = -1e30f; int bi = -1;
            #pragma unroll
            for (int s = 0; s < 19; ++s) {
                int j = lane + 64 * s;
                if (val[s] >= bv) { bv = val[s]; bi = j; }
            }
            #pragma unroll
            for (int o = 32; o > 0; o >>= 1) {
                float ov = __shfl_xor(bv, o);
                int oi = __shfl_xor(bi, o);
                if (ov > bv || (ov == bv && oi > bi)) { bv = ov; bi = oi; }
            }
            if (lane == 0) { topk[9 - sel] = bi; jl[9 - sel] = bi; }
            if ((bi & 63) == lane) val[bi >> 6] = -1e30f;
        }
    }
    __syncthreads();                        // jl + sh_lds ready

    // phase 2: MFMA scores for 10 candidates (2 per wave) + NW DP
    int c1 = jl[2 * w], c2 = jl[2 * w + 1];
    int ptC = (rr < 8) ? (c1 * 5 + min(rr, 4)) : (c2 * 5 + min(rr - 8, 4));
    const short* cp = cdEf + ((size_t)(ptC >> 4) * NCH * 64 + q * 16 + (ptC & 15)) * 8;

    f32x4 acc = (f32x4){0.f, 0.f, 0.f, 0.f};
    #pragma unroll
    for (int c = 0; c < NCH; ++c) {
        short8 sh = *(const short8*)&sh_lds[c * 512 + lane * 8];
        short8 cb = *(const short8*)(cp + c * 512);
        acc = dir ? __builtin_amdgcn_mfma_f32_16x16x32_bf16(cb, sh, acc, 0, 0, 0)
                  : __builtin_amdgcn_mfma_f32_16x16x32_bf16(sh, cb, acc, 0, 0, 0);
    }
    // C layout: m = q*4+reg, n = lane&15
    #pragma unroll
    for (int reg = 0; reg < 4; ++reg) {
        int m = q * 4 + reg, n = rr;
        if (!dir) {
            if (m < 5 && n < 5) sbuf[2 * w][m * 5 + n] = acc[reg];
            if (m < 5 && n >= 8 && n < 13) sbuf[2 * w + 1][m * 5 + (n - 8)] = acc[reg];
        } else {
            if (m < 5 && n < 5) sbuf[2 * w][m * 5 + n] = acc[reg];
            if (m >= 8 && m < 13 && n < 5) sbuf[2 * w + 1][(m - 8) * 5 + n] = acc[reg];
        }
    }
    __syncthreads();

    if (t < 20) {
        int r = t >> 1, rev = t & 1;
        int i = dir ? jl[r] : row;
        int j = dir ? row : jl[r];
        float S[25];
        #pragma unroll
        for (int a = 0; a < 5; ++a) {
            float va = val1[i * NS + a];
            #pragma unroll
            for (int b = 0; b < 5; ++b) {
                float vb = val2[j * NS + b];
                S[a * 5 + b] = (va != 0.0f && vb != 0.0f) ? sbuf[r][a * 5 + b] : -1.0f;
            }
        }
        float M[25];
        #pragma unroll
        for (int x = 0; x < 5; ++x)
            #pragma unroll
            for (int y = 0; y < 5; ++y) {
                if (!dir) M[x * 5 + y] = rev ? S[x * 5 + (4 - y)] : S[x * 5 + y];
                else      M[x * 5 + y] = rev ? S[(4 - y) * 5 + x] : S[y * 5 + x];
            }
        float nwv = nw5(M);
        float* o = dir ? nw2buf : nwout;
        o[row * 20 + rev * 10 + r] = nwv;
    }
}

// ---------------- K4: argmax over 20 + mutual check (single block) --------
__global__ void argmax_final_kernel(const float* __restrict__ nw1, const float* __restrict__ nw2,
                                    const int* __restrict__ topk1, const int* __restrict__ topk2,
                                    float* __restrict__ out) {
    __shared__ int mpre[NLINES];
    __shared__ int m2[NLINES];
    int t = threadIdx.x;               // 0..1023
    for (int qq = t; qq < 2 * NLINES; qq += 1024) {
        int dir = qq / NLINES, row = qq - dir * NLINES;
        const float* nw = (dir ? nw2 : nw1) + row * 20;
        float best = nw[0]; int bi = 0;
        #pragma unroll
        for (int q = 1; q < 20; ++q) {
            float v = nw[q];
            if (v > best) { best = v; bi = q; }
        }
        int m = (dir ? topk2 : topk1)[row * 10 + (bi % 10)];
        if (dir) m2[row] = m; else mpre[row] = m;
    }
    __syncthreads();
    for (int i = t; i < NLINES; i += 1024) {
        int m = mpre[i];
        out[i] = (m2[m] == i) ? (float)m : -1.0f;
    }
}

extern "C" void kernel_launch(void* const* d_in, const int* in_sizes, int n_in,
                              void* d_out, int out_size, void* d_ws, size_t ws_size,
                              hipStream_t stream) {
    const float* lseg1 = (const float*)d_in[0];
    const float* lseg2 = (const float*)d_in[1];
    const float* desc1 = (const float*)d_in[2];
    const float* desc2 = (const float*)d_in[3];
    float* out = (float*)d_out;

    float* wsf = (float*)d_ws;
    size_t off = 0;
    float* val1 = wsf + off;   off += PPAD;
    float* val2 = wsf + off;   off += PPAD;
    float* lsc = wsf + off;    off += (size_t)NLINES * NLINES;
    float* lscT = wsf + off;   off += (size_t)NLINES * NLINES;
    int* topk1 = (int*)(wsf + off); off += NLINES * 10;
    int* topk2 = (int*)(wsf + off); off += NLINES * 10;
    float* nw2buf = wsf + off; off += NLINES * 20;
    short* Aext = (short*)(wsf + off); off += (size_t)PPAD * KEXT / 2;
    short* Bext = (short*)(wsf + off); off += (size_t)PPAD * KEXT / 2;
    float* tdesc1 = wsf + off; off += (size_t)HW * DD;
    float* tdesc2 = wsf + off; off += (size_t)HW * DD;
    size_t need_full = off * sizeof(float);
    int use_t = (ws_size >= need_full) ? 1 : 0;

    if (use_t) {
        transpose_desc<<<dim3(HW / 128, DD / 32, 2), 256, 0, stream>>>(
            desc1, tdesc1, desc2, tdesc2);
    }
    samplepack_kernel<<<dim3(NGRP, 2), 256, 0, stream>>>(
        lseg1, lseg2, tdesc1, tdesc2, desc1, desc2, Aext, Bext, val1, val2, use_t);

    score_kernel<<<dim3(NPAD / 32, NPAD / 32), 256, 0, stream>>>(Aext, Bext, val1, val2,
                                                                 lsc, lscT);

    topk_nw_kernel<<<2 * NLINES, 320, 0, stream>>>(lsc, lscT, Aext, Bext, val1, val2,
                                                   topk1, topk2, out + NLINES, nw2buf);

    argmax_final_kernel<<<1, 1024, 0, stream>>>(out + NLINES, nw2buf, topk1, topk2, out);
}

// Round 14
// 182.165 us; speedup vs baseline: 2.2207x; 1.0025x over previous
//
#include <hip/hip_runtime.h>
#include <hip/hip_bf16.h>

// SOLD2 line matching on MI355X.
// Inputs: line_seg1 (1200,2,2) f32, line_seg2 (1200,2,2) f32,
//         desc1 (1,128,128,128) f32, desc2 (1,128,128,128) f32
// Outputs (concat float32): matches (1200,), nw (1200,20)

#define NLINES 1200
#define NS 5
#define DD 128
#define HH 128
#define WW 128
#define HW (HH*WW)
#define IMGM1 511.0f
#define GAPC 0.1f
#define NPAD 1216          // 38*32
#define PPAD (NPAD*NS)     // 6080 padded points
#define KEXT 384           // 3-term bf16 split: [hi,lo,hi] x [hi,hi,lo]
#define NCH (KEXT/32)      // 12 k-chunks of 32
#define NGRP (PPAD/16)     // 380 16-pt groups

typedef __attribute__((ext_vector_type(8))) short short8;
typedef __attribute__((ext_vector_type(4))) float f32x4;

__device__ __forceinline__ void async_cp16(const void* g, void* l) {
    __builtin_amdgcn_global_load_lds(
        (const __attribute__((address_space(1))) void*)g,
        (__attribute__((address_space(3))) void*)l, 16, 0, 0);
}

// ------ K0: transpose desc [D][H][W] -> [H*W][D], float4 both ways --------
__global__ void transpose_desc(const float* __restrict__ in1, float* __restrict__ out1,
                               const float* __restrict__ in2, float* __restrict__ out2) {
    const float* in = blockIdx.z ? in2 : in1;
    float* out = blockIdx.z ? out2 : out1;
    __shared__ float t[32][132];
    int s0 = blockIdx.x * 128;         // HW dim
    int d0 = blockIdx.y * 32;          // D dim
    int tid = threadIdx.x;
    #pragma unroll
    for (int pass = 0; pass < 4; ++pass) {
        int idx = pass * 256 + tid;    // 0..1023 = 32 d x 32 s-chunks
        int dr = idx >> 5, si = idx & 31;
        float4 v = *(const float4*)&in[(size_t)(d0 + dr) * HW + s0 + 4 * si];
        *(float4*)&t[dr][4 * si] = v;
    }
    __syncthreads();
    #pragma unroll
    for (int pass = 0; pass < 4; ++pass) {
        int idx = pass * 256 + tid;    // 0..1023 = 128 s x 8 d-chunks
        int sr = idx >> 3, di = idx & 7;
        float4 v = { t[4 * di][sr], t[4 * di + 1][sr], t[4 * di + 2][sr], t[4 * di + 3][sr] };
        *(float4*)&out[(size_t)(s0 + sr) * DD + d0 + 4 * di] = v;
    }
}

// ------- K1: fused sample + bilinear + normalize + bf16 split + pack ------
__global__ void samplepack_kernel(const float* __restrict__ lseg1, const float* __restrict__ lseg2,
                                  const float* __restrict__ tdesc1, const float* __restrict__ tdesc2,
                                  const float* __restrict__ desc1, const float* __restrict__ desc2,
                                  short* __restrict__ Aext, short* __restrict__ Bext,
                                  float* __restrict__ val1, float* __restrict__ val2,
                                  int use_t) {
    int side = blockIdx.y;
    const float* lseg = side ? lseg2 : lseg1;
    const float* tdesc = side ? tdesc2 : tdesc1;
    const float* desc = side ? desc2 : desc1;
    short* Ef = side ? Bext : Aext;
    float* valout = side ? val2 : val1;
    int arole = side ? 0 : 1;          // A: [hi,lo,hi]; B: [hi,hi,lo]

    __shared__ float ds[16][129];
    int g = blockIdx.x;
    int t = threadIdx.x;
    int lane = t & 63, w = t >> 6;

    #pragma unroll
    for (int s = 0; s < 4; ++s) {
        int r = w * 4 + s;
        int pt = g * 16 + r;
        int line = pt / NS;
        int k = pt - line * NS;

        float sy = 0.f, sx = 0.f, ey = 0.f, ex = 0.f;
        if (line < NLINES) {
            sy = lseg[line * 4 + 0]; sx = lseg[line * 4 + 1];
            ey = lseg[line * 4 + 2]; ex = lseg[line * 4 + 3];
        }
        float dy = ey - sy, dx = ex - sx;
        float len = sqrtf(dy * dy + dx * dx);
        float ns = floorf(len * 0.125f);
        ns = fminf(fmaxf(ns, 2.0f), 5.0f);
        float kf = (float)k;
        float validf = (kf < ns) ? 1.0f : 0.0f;
        float py = sy + kf * (dy / (ns - 1.0f));
        float px = sx + kf * (dx / (ns - 1.0f));
        if (validf == 0.0f) { py = 0.0f; px = 0.0f; }

        float xn = 2.0f * px / IMGM1 - 1.0f;
        float yn = 2.0f * py / IMGM1 - 1.0f;
        float ix = ((xn + 1.0f) * (float)WW - 1.0f) * 0.5f;
        float iy = ((yn + 1.0f) * (float)HH - 1.0f) * 0.5f;
        float x0f = floorf(ix), y0f = floorf(iy);
        float wx = ix - x0f, wy = iy - y0f;
        int x0 = (int)x0f, y0 = (int)y0f;

        float w00 = (1.0f - wx) * (1.0f - wy);
        float w10 = wx * (1.0f - wy);
        float w01 = (1.0f - wx) * wy;
        float w11 = wx * wy;

        float v0 = 0.0f, v1 = 0.0f;
        int xs[4] = { x0, x0 + 1, x0,     x0 + 1 };
        int ys[4] = { y0, y0,     y0 + 1, y0 + 1 };
        float ws4[4] = { w00, w10, w01, w11 };
        #pragma unroll
        for (int c = 0; c < 4; ++c) {
            int xi = xs[c], yi = ys[c];
            float inb = (xi >= 0 && xi < WW && yi >= 0 && yi < HH) ? 1.0f : 0.0f;
            int xc = min(max(xi, 0), WW - 1);
            int yc = min(max(yi, 0), HH - 1);
            if (use_t) {
                int base = (yc * WW + xc) * DD;
                v0 += tdesc[base + lane] * inb * ws4[c];
                v1 += tdesc[base + 64 + lane] * inb * ws4[c];
            } else {
                int base = yc * WW + xc;
                v0 += desc[lane * HW + base] * inb * ws4[c];
                v1 += desc[(lane + 64) * HW + base] * inb * ws4[c];
            }
        }
        float ss = v0 * v0 + v1 * v1;
        #pragma unroll
        for (int o = 32; o > 0; o >>= 1) ss += __shfl_xor(ss, o);
        if (ss == 0.0f) ss = 1.0f;   // padding lines: avoid 0/0 NaN
        float nrm = sqrtf(ss);
        ds[r][lane] = v0 / nrm;
        ds[r][64 + lane] = v1 / nrm;
        if (lane == 0) valout[pt] = (line < NLINES) ? validf : 0.0f;
    }
    __syncthreads();

    #pragma unroll
    for (int it = 0; it < 3; ++it) {
        int idx = it * 256 + t;        // 0..767 = 12 chunks x 64 lanes
        int c = idx >> 6, l = idx & 63;
        int q = l >> 4, r = l & 15;
        short8 outv;
        #pragma unroll
        for (int jj = 0; jj < 8; ++jj) {
            int kext = c * 32 + q * 8 + jj;
            int term = kext >> 7, k = kext & 127;
            float x = ds[r][k];
            __hip_bfloat16 h = __float2bfloat16(x);
            short v = *(short*)&h;
            bool lo_term = arole ? (term == 1) : (term == 2);
            if (lo_term) {
                float hf = __bfloat162float(h);
                __hip_bfloat16 lw = __float2bfloat16(x - hf);
                v = *(short*)&lw;
            }
            outv[jj] = v;
        }
        *(short8*)&Ef[((size_t)(g * NCH + c) * 64 + l) * 8] = outv;
    }
}

// ---------------- K2: MFMA score GEMM + fused per-line-pair reduction -----
// R11 proven structure (51.1 us): A register double-buffer direct-global,
// B LDS-staged once per block, bounds(256,2). bounds(256,4) spills the
// accumulator (R12: 583 MB scratch writes, 6x slower).
__launch_bounds__(256, 2)
__global__ void score_kernel(const short* __restrict__ Af, const short* __restrict__ Bf,
                             const float* __restrict__ val1, const float* __restrict__ val2,
                             float* __restrict__ lsc, float* __restrict__ lscT) {
    __shared__ union {
        struct { short B[2][5120]; } st;                       // 20480 B
        struct { float dump[80 * 161]; float red[16][33]; } ep; // 53632 B
    } u;

    const int t = threadIdx.x;
    const int lane = t & 63;
    const int w = t >> 6;           // wave 0..3
    const int wm = w >> 1;          // 0..1 row half
    const int wn = w & 1;           // 0..1 col half
    const int gA0 = blockIdx.x * 10;   // first 16-pt group of A side
    const int gB0 = blockIdx.y * 10;

    const short* pa[5];
    #pragma unroll
    for (int ti = 0; ti < 5; ++ti)
        pa[ti] = Af + ((size_t)(gA0 + 5 * wm + ti) * NCH * 64 + lane) * 8;

    f32x4 acc[5][5];
    #pragma unroll
    for (int a = 0; a < 5; ++a)
        #pragma unroll
        for (int b = 0; b < 5; ++b)
            acc[a][b] = (f32x4){0.f, 0.f, 0.f, 0.f};

    // stage B chunk c into buffer b: waves 0,1 handle 5 groups each
    auto stageB = [&](int c, int b) {
        if (w < 2) {
            #pragma unroll
            for (int p = 0; p < 5; ++p) {
                int gi = w * 5 + p;
                const short* g = Bf + ((size_t)((gB0 + gi) * NCH + c) * 64 + lane) * 8;
                async_cp16(g, &u.st.B[b][gi * 512]);
            }
        }
    };

    short8 ca[5], na[5];
    stageB(0, 0);
    #pragma unroll
    for (int ti = 0; ti < 5; ++ti) ca[ti] = *(const short8*)(pa[ti]);

    #pragma unroll
    for (int c = 0; c < NCH; ++c) {
        __syncthreads();               // drains stage(c) + A-loads(c); both used now
        if (c + 1 < NCH) {
            stageB(c + 1, (c + 1) & 1);
            #pragma unroll
            for (int ti = 0; ti < 5; ++ti)
                na[ti] = *(const short8*)(pa[ti] + (c + 1) * 512);
        }
        short8 bf_[5];
        #pragma unroll
        for (int tj = 0; tj < 5; ++tj)
            bf_[tj] = *(const short8*)&u.st.B[c & 1][(5 * wn + tj) * 512 + lane * 8];
        #pragma unroll
        for (int ti = 0; ti < 5; ++ti)
            #pragma unroll
            for (int tj = 0; tj < 5; ++tj)
                acc[ti][tj] = __builtin_amdgcn_mfma_f32_16x16x32_bf16(
                    ca[ti], bf_[tj], acc[ti][tj], 0, 0, 0);
        #pragma unroll
        for (int ti = 0; ti < 5; ++ti) ca[ti] = na[ti];
    }

    const int i0l = blockIdx.x * 32;
    const int j0l = blockIdx.y * 32;
    #pragma unroll
    for (int p = 0; p < 2; ++p) {
        __syncthreads();
        if (wm == p) {
            #pragma unroll
            for (int ti = 0; ti < 5; ++ti) {
                #pragma unroll
                for (int reg = 0; reg < 4; ++reg) {
                    int rloc = 16 * ti + (lane >> 4) * 4 + reg;
                    #pragma unroll
                    for (int tj = 0; tj < 5; ++tj) {
                        int col = 80 * wn + 16 * tj + (lane & 15);
                        u.ep.dump[rloc * 161 + col] = acc[ti][tj][reg];
                    }
                }
            }
        }
        __syncthreads();
        // pass 1: reduce once per pair, write lsc (coalesced in j), park in red
        #pragma unroll
        for (int e = 0; e < 2; ++e) {
            int q = t * 2 + e;            // 0..511
            int li = q >> 5, lj = q & 31;
            int i = i0l + 16 * p + li;
            int j = j0l + lj;
            float S[5][5];
            #pragma unroll
            for (int a = 0; a < 5; ++a) {
                float va = val1[i * NS + a];   // i < NPAD always: safe
                #pragma unroll
                for (int b = 0; b < 5; ++b) {
                    float vb = val2[j * NS + b];
                    float sc = u.ep.dump[(li * 5 + a) * 161 + (lj * 5 + b)];
                    S[a][b] = (va != 0.0f && vb != 0.0f) ? sc : -1.0f;
                }
            }
            float sum1 = 0.0f, cnt1 = 0.0f;
            #pragma unroll
            for (int a = 0; a < 5; ++a) {
                float r = S[a][0];
                #pragma unroll
                for (int b = 1; b < 5; ++b) r = fmaxf(r, S[a][b]);
                float v = (r != -1.0f) ? 1.0f : 0.0f;
                sum1 += r * v; cnt1 += v;
            }
            float sum2 = 0.0f, cnt2 = 0.0f;
            #pragma unroll
            for (int b = 0; b < 5; ++b) {
                float r = S[0][b];
                #pragma unroll
                for (int a = 1; a < 5; ++a) r = fmaxf(r, S[a][b]);
                float v = (r != -1.0f) ? 1.0f : 0.0f;
                sum2 += r * v; cnt2 += v;
            }
            float res = (sum1 / cnt1 + sum2 / cnt2) * 0.5f;
            u.ep.red[li][lj] = res;
            if (i < NLINES && j < NLINES) lsc[i * NLINES + j] = res;
        }
        __syncthreads();
        // pass 2: lscT from red, coalesced in i
        #pragma unroll
        for (int e = 0; e < 2; ++e) {
            int q = t + 256 * e;          // 0..511
            int li = q & 15, lj = q >> 4;
            int i = i0l + 16 * p + li;
            int j = j0l + lj;
            if (i < NLINES && j < NLINES) lscT[j * NLINES + i] = u.ep.red[li][lj];
        }
    }
}

// ------- K3: fused per-row top-10 + Needleman-Wunsch (320 thr = 5 waves) --
// Phase 0: stage shared-line fragments to LDS (drains during topk).
// Phase 1: EACH wave selects top-10 of its 240-element slice in registers
// (no block barriers, all waves busy); wave lists come out in global
// (value desc, index desc) selection order, so a single-lane 5-way merge
// reproduces stable-argsort exactly. One barrier total.
// Phase 2: wave w -> candidates 2w,2w+1 via one 12-chunk MFMA; 20-lane DP.
__device__ __forceinline__ float nw5(const float* M) {
    float F[6] = {0, 0, 0, 0, 0, 0};
    #pragma unroll
    for (int x = 0; x < 5; ++x) {
        float diag = F[0];
        float left = 0.0f;
        #pragma unroll
        for (int y = 1; y <= 5; ++y) {
            float up = F[y];
            float cur = fmaxf(fmaxf(left, up), diag + (M[x * 5 + y - 1] - GAPC));
            F[y] = cur; left = cur; diag = up;
        }
    }
    return F[5];
}

__global__ void topk_nw_kernel(const float* __restrict__ lsc, const float* __restrict__ lscT,
                               const short* __restrict__ Af, const short* __restrict__ Bf,
                               const float* __restrict__ val1, const float* __restrict__ val2,
                               int* __restrict__ topk1, int* __restrict__ topk2,
                               float* __restrict__ nwout, float* __restrict__ nw2buf) {
    __shared__ short sh_lds[NCH * 512];     // 12 KB: shared line fragments
    __shared__ float sbuf[10][25];
    __shared__ int jl[10];
    __shared__ float wtv[5][10];
    __shared__ int wti[5][10];
    int rb = blockIdx.x;                    // 0..2399
    int dir = (rb >= NLINES) ? 1 : 0;
    int row = rb - dir * NLINES;
    int t = threadIdx.x;                    // 0..319
    int w = t >> 6;                         // wave 0..4
    int lane = t & 63;
    int q = lane >> 4, rr = lane & 15;

    const short* shEf = dir ? Bf : Af;      // shared side
    const short* cdEf = dir ? Af : Bf;      // candidate side
    const float* ls = dir ? (lscT + (size_t)row * NLINES) : (lsc + (size_t)row * NLINES);
    int* topk = dir ? (topk2 + row * 10) : (topk1 + row * 10);

    // phase 0: stage shared-line fragments (drains during topk)
    for (int idx = t; idx < NCH * 64; idx += 320) {
        int c = idx >> 6, l = idx & 63;
        int lq = l >> 4, lr = l & 15;
        int ptS = row * 5 + min(lr, 4);
        const short* gp = shEf + ((size_t)(ptS >> 4) * NCH * 64 + lq * 16 + (ptS & 15)) * 8
                               + (size_t)c * 512;
        *(short8*)&sh_lds[c * 512 + l * 8] = *(const short8*)gp;
    }

    // phase 1a: per-wave top-10 over its 240-slice (registers + shuffles)
    float val[4];
    #pragma unroll
    for (int s = 0; s < 4; ++s) {
        int j = t + 320 * s;
        val[s] = (j < NLINES) ? ls[j] : -1e30f;
    }
    for (int sel = 0; sel < 10; ++sel) {
        float bv = -1e30f; int bi = -1;
        #pragma unroll
        for (int s = 0; s < 4; ++s) {
            int j = t + 320 * s;
            if (val[s] >= bv) { bv = val[s]; bi = j; }
        }
        #pragma unroll
        for (int o = 32; o > 0; o >>= 1) {
            float ov = __shfl_xor(bv, o);
            int oi = __shfl_xor(bi, o);
            if (ov > bv || (ov == bv && oi > bi)) { bv = ov; bi = oi; }
        }
        if (lane == 0) { wtv[w][sel] = bv; wti[w][sel] = bi; }
        if (bi >= 0 && (bi % 320) == t) val[bi / 320] = -1e30f;
    }
    __syncthreads();
    // phase 1b: single-lane 5-way merge of sorted wave lists
    if (t == 0) {
        int head[5] = {0, 0, 0, 0, 0};
        for (int sel = 0; sel < 10; ++sel) {
            float fv = -1e30f; int fi = -1, fw = 0;
            #pragma unroll
            for (int ww = 0; ww < 5; ++ww) {
                if (head[ww] < 10) {
                    float v = wtv[ww][head[ww]];
                    int ii = wti[ww][head[ww]];
                    if (v > fv || (v == fv && ii > fi)) { fv = v; fi = ii; fw = ww; }
                }
            }
            head[fw]++;
            topk[9 - sel] = fi;
            jl[9 - sel] = fi;
        }
    }
    __syncthreads();                        // jl + sh_lds ready

    // phase 2: MFMA scores for 10 candidates (2 per wave) + NW DP
    int c1 = jl[2 * w], c2 = jl[2 * w + 1];
    int ptC = (rr < 8) ? (c1 * 5 + min(rr, 4)) : (c2 * 5 + min(rr - 8, 4));
    const short* cp = cdEf + ((size_t)(ptC >> 4) * NCH * 64 + q * 16 + (ptC & 15)) * 8;

    f32x4 acc = (f32x4){0.f, 0.f, 0.f, 0.f};
    #pragma unroll
    for (int c = 0; c < NCH; ++c) {
        short8 sh = *(const short8*)&sh_lds[c * 512 + lane * 8];
        short8 cb = *(const short8*)(cp + c * 512);
        acc = dir ? __builtin_amdgcn_mfma_f32_16x16x32_bf16(cb, sh, acc, 0, 0, 0)
                  : __builtin_amdgcn_mfma_f32_16x16x32_bf16(sh, cb, acc, 0, 0, 0);
    }
    // C layout: m = q*4+reg, n = lane&15
    #pragma unroll
    for (int reg = 0; reg < 4; ++reg) {
        int m = q * 4 + reg, n = rr;
        if (!dir) {
            if (m < 5 && n < 5) sbuf[2 * w][m * 5 + n] = acc[reg];
            if (m < 5 && n >= 8 && n < 13) sbuf[2 * w + 1][m * 5 + (n - 8)] = acc[reg];
        } else {
            if (m < 5 && n < 5) sbuf[2 * w][m * 5 + n] = acc[reg];
            if (m >= 8 && m < 13 && n < 5) sbuf[2 * w + 1][(m - 8) * 5 + n] = acc[reg];
        }
    }
    __syncthreads();

    if (t < 20) {
        int r = t >> 1, rev = t & 1;
        int i = dir ? jl[r] : row;
        int j = dir ? row : jl[r];
        float S[25];
        #pragma unroll
        for (int a = 0; a < 5; ++a) {
            float va = val1[i * NS + a];
            #pragma unroll
            for (int b = 0; b < 5; ++b) {
                float vb = val2[j * NS + b];
                S[a * 5 + b] = (va != 0.0f && vb != 0.0f) ? sbuf[r][a * 5 + b] : -1.0f;
            }
        }
        float M[25];
        #pragma unroll
        for (int x = 0; x < 5; ++x)
            #pragma unroll
            for (int y = 0; y < 5; ++y) {
                if (!dir) M[x * 5 + y] = rev ? S[x * 5 + (4 - y)] : S[x * 5 + y];
                else      M[x * 5 + y] = rev ? S[(4 - y) * 5 + x] : S[y * 5 + x];
            }
        float nwv = nw5(M);
        float* o = dir ? nw2buf : nwout;
        o[row * 20 + rev * 10 + r] = nwv;
    }
}

// ---------------- K4: argmax over 20 + mutual check (single block) --------
__global__ void argmax_final_kernel(const float* __restrict__ nw1, const float* __restrict__ nw2,
                                    const int* __restrict__ topk1, const int* __restrict__ topk2,
                                    float* __restrict__ out) {
    __shared__ int mpre[NLINES];
    __shared__ int m2[NLINES];
    int t = threadIdx.x;               // 0..1023
    for (int qq = t; qq < 2 * NLINES; qq += 1024) {
        int dir = qq / NLINES, row = qq - dir * NLINES;
        const float* nw = (dir ? nw2 : nw1) + row * 20;
        float best = nw[0]; int bi = 0;
        #pragma unroll
        for (int q = 1; q < 20; ++q) {
            float v = nw[q];
            if (v > best) { best = v; bi = q; }
        }
        int m = (dir ? topk2 : topk1)[row * 10 + (bi % 10)];
        if (dir) m2[row] = m; else mpre[row] = m;
    }
    __syncthreads();
    for (int i = t; i < NLINES; i += 1024) {
        int m = mpre[i];
        out[i] = (m2[m] == i) ? (float)m : -1.0f;
    }
}

extern "C" void kernel_launch(void* const* d_in, const int* in_sizes, int n_in,
                              void* d_out, int out_size, void* d_ws, size_t ws_size,
                              hipStream_t stream) {
    const float* lseg1 = (const float*)d_in[0];
    const float* lseg2 = (const float*)d_in[1];
    const float* desc1 = (const float*)d_in[2];
    const float* desc2 = (const float*)d_in[3];
    float* out = (float*)d_out;

    float* wsf = (float*)d_ws;
    size_t off = 0;
    float* val1 = wsf + off;   off += PPAD;
    float* val2 = wsf + off;   off += PPAD;
    float* lsc = wsf + off;    off += (size_t)NLINES * NLINES;
    float* lscT = wsf + off;   off += (size_t)NLINES * NLINES;
    int* topk1 = (int*)(wsf + off); off += NLINES * 10;
    int* topk2 = (int*)(wsf + off); off += NLINES * 10;
    float* nw2buf = wsf + off; off += NLINES * 20;
    short* Aext = (short*)(wsf + off); off += (size_t)PPAD * KEXT / 2;
    short* Bext = (short*)(wsf + off); off += (size_t)PPAD * KEXT / 2;
    float* tdesc1 = wsf + off; off += (size_t)HW * DD;
    float* tdesc2 = wsf + off; off += (size_t)HW * DD;
    size_t need_full = off * sizeof(float);
    int use_t = (ws_size >= need_full) ? 1 : 0;

    if (use_t) {
        transpose_desc<<<dim3(HW / 128, DD / 32, 2), 256, 0, stream>>>(
            desc1, tdesc1, desc2, tdesc2);
    }
    samplepack_kernel<<<dim3(NGRP, 2), 256, 0, stream>>>(
        lseg1, lseg2, tdesc1, tdesc2, desc1, desc2, Aext, Bext, val1, val2, use_t);

    score_kernel<<<dim3(NPAD / 32, NPAD / 32), 256, 0, stream>>>(Aext, Bext, val1, val2,
                                                                 lsc, lscT);

    topk_nw_kernel<<<2 * NLINES, 320, 0, stream>>>(lsc, lscT, Aext, Bext, val1, val2,
                                                   topk1, topk2, out + NLINES, nw2buf);

    argmax_final_kernel<<<1, 1024, 0, stream>>>(out + NLINES, nw2buf, topk1, topk2, out);
}

// Round 15
// 180.808 us; speedup vs baseline: 2.2374x; 1.0075x over previous
//
#include <hip/hip_runtime.h>
#include <hip/hip_bf16.h>

// SOLD2 line matching on MI355X.
// Inputs: line_seg1 (1200,2,2) f32, line_seg2 (1200,2,2) f32,
//         desc1 (1,128,128,128) f32, desc2 (1,128,128,128) f32
// Outputs (concat float32): matches (1200,), nw (1200,20)

#define NLINES 1200
#define NS 5
#define DD 128
#define HH 128
#define WW 128
#define HW (HH*WW)
#define IMGM1 511.0f
#define GAPC 0.1f
#define NPAD 1216          // 38*32
#define PPAD (NPAD*NS)     // 6080 padded points
#define KEXT 384           // 3-term bf16 split: [hi,lo,hi] x [hi,hi,lo]
#define NCH (KEXT/32)      // 12 k-chunks of 32
#define NGRP (PPAD/16)     // 380 16-pt groups

typedef __attribute__((ext_vector_type(8))) short short8;
typedef __attribute__((ext_vector_type(4))) float f32x4;

__device__ __forceinline__ void async_cp16(const void* g, void* l) {
    __builtin_amdgcn_global_load_lds(
        (const __attribute__((address_space(1))) void*)g,
        (__attribute__((address_space(3))) void*)l, 16, 0, 0);
}

// ------ K0: transpose desc [D][H][W] -> [H*W][D], float4 both ways --------
__global__ void transpose_desc(const float* __restrict__ in1, float* __restrict__ out1,
                               const float* __restrict__ in2, float* __restrict__ out2) {
    const float* in = blockIdx.z ? in2 : in1;
    float* out = blockIdx.z ? out2 : out1;
    __shared__ float t[32][132];
    int s0 = blockIdx.x * 128;         // HW dim
    int d0 = blockIdx.y * 32;          // D dim
    int tid = threadIdx.x;
    #pragma unroll
    for (int pass = 0; pass < 4; ++pass) {
        int idx = pass * 256 + tid;    // 0..1023 = 32 d x 32 s-chunks
        int dr = idx >> 5, si = idx & 31;
        float4 v = *(const float4*)&in[(size_t)(d0 + dr) * HW + s0 + 4 * si];
        *(float4*)&t[dr][4 * si] = v;
    }
    __syncthreads();
    #pragma unroll
    for (int pass = 0; pass < 4; ++pass) {
        int idx = pass * 256 + tid;    // 0..1023 = 128 s x 8 d-chunks
        int sr = idx >> 3, di = idx & 7;
        float4 v = { t[4 * di][sr], t[4 * di + 1][sr], t[4 * di + 2][sr], t[4 * di + 3][sr] };
        *(float4*)&out[(size_t)(s0 + sr) * DD + d0 + 4 * di] = v;
    }
}

// ------- K1: fused sample + bilinear + normalize + bf16 split + pack ------
// 1024 threads = 16 waves, one point per wave (serial depth 1, was 4).
__global__ void samplepack_kernel(const float* __restrict__ lseg1, const float* __restrict__ lseg2,
                                  const float* __restrict__ tdesc1, const float* __restrict__ tdesc2,
                                  const float* __restrict__ desc1, const float* __restrict__ desc2,
                                  short* __restrict__ Aext, short* __restrict__ Bext,
                                  float* __restrict__ val1, float* __restrict__ val2,
                                  int use_t) {
    int side = blockIdx.y;
    const float* lseg = side ? lseg2 : lseg1;
    const float* tdesc = side ? tdesc2 : tdesc1;
    const float* desc = side ? desc2 : desc1;
    short* Ef = side ? Bext : Aext;
    float* valout = side ? val2 : val1;
    int arole = side ? 0 : 1;          // A: [hi,lo,hi]; B: [hi,hi,lo]

    __shared__ float ds[16][129];
    int g = blockIdx.x;
    int t = threadIdx.x;               // 0..1023
    int lane = t & 63, w = t >> 6;     // wave 0..15 = point index in group

    {
        int r = w;
        int pt = g * 16 + r;
        int line = pt / NS;
        int k = pt - line * NS;

        float sy = 0.f, sx = 0.f, ey = 0.f, ex = 0.f;
        if (line < NLINES) {
            sy = lseg[line * 4 + 0]; sx = lseg[line * 4 + 1];
            ey = lseg[line * 4 + 2]; ex = lseg[line * 4 + 3];
        }
        float dy = ey - sy, dx = ex - sx;
        float len = sqrtf(dy * dy + dx * dx);
        float ns = floorf(len * 0.125f);
        ns = fminf(fmaxf(ns, 2.0f), 5.0f);
        float kf = (float)k;
        float validf = (kf < ns) ? 1.0f : 0.0f;
        float py = sy + kf * (dy / (ns - 1.0f));
        float px = sx + kf * (dx / (ns - 1.0f));
        if (validf == 0.0f) { py = 0.0f; px = 0.0f; }

        float xn = 2.0f * px / IMGM1 - 1.0f;
        float yn = 2.0f * py / IMGM1 - 1.0f;
        float ix = ((xn + 1.0f) * (float)WW - 1.0f) * 0.5f;
        float iy = ((yn + 1.0f) * (float)HH - 1.0f) * 0.5f;
        float x0f = floorf(ix), y0f = floorf(iy);
        float wx = ix - x0f, wy = iy - y0f;
        int x0 = (int)x0f, y0 = (int)y0f;

        float w00 = (1.0f - wx) * (1.0f - wy);
        float w10 = wx * (1.0f - wy);
        float w01 = (1.0f - wx) * wy;
        float w11 = wx * wy;

        float v0 = 0.0f, v1 = 0.0f;
        int xs[4] = { x0, x0 + 1, x0,     x0 + 1 };
        int ys[4] = { y0, y0,     y0 + 1, y0 + 1 };
        float ws4[4] = { w00, w10, w01, w11 };
        #pragma unroll
        for (int c = 0; c < 4; ++c) {
            int xi = xs[c], yi = ys[c];
            float inb = (xi >= 0 && xi < WW && yi >= 0 && yi < HH) ? 1.0f : 0.0f;
            int xc = min(max(xi, 0), WW - 1);
            int yc = min(max(yi, 0), HH - 1);
            if (use_t) {
                int base = (yc * WW + xc) * DD;
                v0 += tdesc[base + lane] * inb * ws4[c];
                v1 += tdesc[base + 64 + lane] * inb * ws4[c];
            } else {
                int base = yc * WW + xc;
                v0 += desc[lane * HW + base] * inb * ws4[c];
                v1 += desc[(lane + 64) * HW + base] * inb * ws4[c];
            }
        }
        float ss = v0 * v0 + v1 * v1;
        #pragma unroll
        for (int o = 32; o > 0; o >>= 1) ss += __shfl_xor(ss, o);
        if (ss == 0.0f) ss = 1.0f;   // padding lines: avoid 0/0 NaN
        float nrm = sqrtf(ss);
        ds[r][lane] = v0 / nrm;
        ds[r][64 + lane] = v1 / nrm;
        if (lane == 0) valout[pt] = (line < NLINES) ? validf : 0.0f;
    }
    __syncthreads();

    if (t < 768) {                     // 12 chunks x 64 lanes
        int c = t >> 6, l = t & 63;
        int q = l >> 4, r = l & 15;
        short8 outv;
        #pragma unroll
        for (int jj = 0; jj < 8; ++jj) {
            int kext = c * 32 + q * 8 + jj;
            int term = kext >> 7, k = kext & 127;
            float x = ds[r][k];
            __hip_bfloat16 h = __float2bfloat16(x);
            short v = *(short*)&h;
            bool lo_term = arole ? (term == 1) : (term == 2);
            if (lo_term) {
                float hf = __bfloat162float(h);
                __hip_bfloat16 lw = __float2bfloat16(x - hf);
                v = *(short*)&lw;
            }
            outv[jj] = v;
        }
        *(short8*)&Ef[((size_t)(g * NCH + c) * 64 + l) * 8] = outv;
    }
}

// ---------------- K2: MFMA score GEMM + fused per-line-pair reduction -----
// R11 proven structure (51.1 us): A register double-buffer direct-global,
// B LDS-staged once per block, bounds(256,2). bounds(256,4) spills the
// accumulator (R12: 583 MB scratch writes, 6x slower).
__launch_bounds__(256, 2)
__global__ void score_kernel(const short* __restrict__ Af, const short* __restrict__ Bf,
                             const float* __restrict__ val1, const float* __restrict__ val2,
                             float* __restrict__ lsc, float* __restrict__ lscT) {
    __shared__ union {
        struct { short B[2][5120]; } st;                       // 20480 B
        struct { float dump[80 * 161]; float red[16][33]; } ep; // 53632 B
    } u;

    const int t = threadIdx.x;
    const int lane = t & 63;
    const int w = t >> 6;           // wave 0..3
    const int wm = w >> 1;          // 0..1 row half
    const int wn = w & 1;           // 0..1 col half
    const int gA0 = blockIdx.x * 10;   // first 16-pt group of A side
    const int gB0 = blockIdx.y * 10;

    const short* pa[5];
    #pragma unroll
    for (int ti = 0; ti < 5; ++ti)
        pa[ti] = Af + ((size_t)(gA0 + 5 * wm + ti) * NCH * 64 + lane) * 8;

    f32x4 acc[5][5];
    #pragma unroll
    for (int a = 0; a < 5; ++a)
        #pragma unroll
        for (int b = 0; b < 5; ++b)
            acc[a][b] = (f32x4){0.f, 0.f, 0.f, 0.f};

    // stage B chunk c into buffer b: waves 0,1 handle 5 groups each
    auto stageB = [&](int c, int b) {
        if (w < 2) {
            #pragma unroll
            for (int p = 0; p < 5; ++p) {
                int gi = w * 5 + p;
                const short* g = Bf + ((size_t)((gB0 + gi) * NCH + c) * 64 + lane) * 8;
                async_cp16(g, &u.st.B[b][gi * 512]);
            }
        }
    };

    short8 ca[5], na[5];
    stageB(0, 0);
    #pragma unroll
    for (int ti = 0; ti < 5; ++ti) ca[ti] = *(const short8*)(pa[ti]);

    #pragma unroll
    for (int c = 0; c < NCH; ++c) {
        __syncthreads();               // drains stage(c) + A-loads(c); both used now
        if (c + 1 < NCH) {
            stageB(c + 1, (c + 1) & 1);
            #pragma unroll
            for (int ti = 0; ti < 5; ++ti)
                na[ti] = *(const short8*)(pa[ti] + (c + 1) * 512);
        }
        short8 bf_[5];
        #pragma unroll
        for (int tj = 0; tj < 5; ++tj)
            bf_[tj] = *(const short8*)&u.st.B[c & 1][(5 * wn + tj) * 512 + lane * 8];
        #pragma unroll
        for (int ti = 0; ti < 5; ++ti)
            #pragma unroll
            for (int tj = 0; tj < 5; ++tj)
                acc[ti][tj] = __builtin_amdgcn_mfma_f32_16x16x32_bf16(
                    ca[ti], bf_[tj], acc[ti][tj], 0, 0, 0);
        #pragma unroll
        for (int ti = 0; ti < 5; ++ti) ca[ti] = na[ti];
    }

    const int i0l = blockIdx.x * 32;
    const int j0l = blockIdx.y * 32;
    #pragma unroll
    for (int p = 0; p < 2; ++p) {
        __syncthreads();
        if (wm == p) {
            #pragma unroll
            for (int ti = 0; ti < 5; ++ti) {
                #pragma unroll
                for (int reg = 0; reg < 4; ++reg) {
                    int rloc = 16 * ti + (lane >> 4) * 4 + reg;
                    #pragma unroll
                    for (int tj = 0; tj < 5; ++tj) {
                        int col = 80 * wn + 16 * tj + (lane & 15);
                        u.ep.dump[rloc * 161 + col] = acc[ti][tj][reg];
                    }
                }
            }
        }
        __syncthreads();
        // pass 1: reduce once per pair, write lsc (coalesced in j), park in red
        #pragma unroll
        for (int e = 0; e < 2; ++e) {
            int q = t * 2 + e;            // 0..511
            int li = q >> 5, lj = q & 31;
            int i = i0l + 16 * p + li;
            int j = j0l + lj;
            float S[5][5];
            #pragma unroll
            for (int a = 0; a < 5; ++a) {
                float va = val1[i * NS + a];   // i < NPAD always: safe
                #pragma unroll
                for (int b = 0; b < 5; ++b) {
                    float vb = val2[j * NS + b];
                    float sc = u.ep.dump[(li * 5 + a) * 161 + (lj * 5 + b)];
                    S[a][b] = (va != 0.0f && vb != 0.0f) ? sc : -1.0f;
                }
            }
            float sum1 = 0.0f, cnt1 = 0.0f;
            #pragma unroll
            for (int a = 0; a < 5; ++a) {
                float r = S[a][0];
                #pragma unroll
                for (int b = 1; b < 5; ++b) r = fmaxf(r, S[a][b]);
                float v = (r != -1.0f) ? 1.0f : 0.0f;
                sum1 += r * v; cnt1 += v;
            }
            float sum2 = 0.0f, cnt2 = 0.0f;
            #pragma unroll
            for (int b = 0; b < 5; ++b) {
                float r = S[0][b];
                #pragma unroll
                for (int a = 1; a < 5; ++a) r = fmaxf(r, S[a][b]);
                float v = (r != -1.0f) ? 1.0f : 0.0f;
                sum2 += r * v; cnt2 += v;
            }
            float res = (sum1 / cnt1 + sum2 / cnt2) * 0.5f;
            u.ep.red[li][lj] = res;
            if (i < NLINES && j < NLINES) lsc[i * NLINES + j] = res;
        }
        __syncthreads();
        // pass 2: lscT from red, coalesced in i
        #pragma unroll
        for (int e = 0; e < 2; ++e) {
            int q = t + 256 * e;          // 0..511
            int li = q & 15, lj = q >> 4;
            int i = i0l + 16 * p + li;
            int j = j0l + lj;
            if (i < NLINES && j < NLINES) lscT[j * NLINES + i] = u.ep.red[li][lj];
        }
    }
}

// ------- K3: fused top-10 + NW + per-row argmax (320 thr = 5 waves) -------
// Phase 0: stage shared-line fragments to LDS (drains during topk).
// Phase 1a: per-wave top-10 of its 240-slice (registers+shuffles, no
// barriers); 1b: single-lane 5-way merge (stable-argsort order).
// Phase 2: wave w -> candidates 2w,2w+1 via one 12-chunk MFMA; 20-lane DP.
// Phase 3: per-row argmax over the 20 nw values (first-max = jnp.argmax)
// -> mpre/m2 written directly; no topk/nw global round-trip for argmax.
__device__ __forceinline__ float nw5(const float* M) {
    float F[6] = {0, 0, 0, 0, 0, 0};
    #pragma unroll
    for (int x = 0; x < 5; ++x) {
        float diag = F[0];
        float left = 0.0f;
        #pragma unroll
        for (int y = 1; y <= 5; ++y) {
            float up = F[y];
            float cur = fmaxf(fmaxf(left, up), diag + (M[x * 5 + y - 1] - GAPC));
            F[y] = cur; left = cur; diag = up;
        }
    }
    return F[5];
}

__global__ void topk_nw_kernel(const float* __restrict__ lsc, const float* __restrict__ lscT,
                               const short* __restrict__ Af, const short* __restrict__ Bf,
                               const float* __restrict__ val1, const float* __restrict__ val2,
                               float* __restrict__ nwout, float* __restrict__ nw2buf,
                               int* __restrict__ mpre, int* __restrict__ m2) {
    __shared__ short sh_lds[NCH * 512];     // 12 KB: shared line fragments
    __shared__ float sbuf[10][25];
    __shared__ int jl[10];
    __shared__ float wtv[5][10];
    __shared__ int wti[5][10];
    __shared__ float nwa[20];
    int rb = blockIdx.x;                    // 0..2399
    int dir = (rb >= NLINES) ? 1 : 0;
    int row = rb - dir * NLINES;
    int t = threadIdx.x;                    // 0..319
    int w = t >> 6;                         // wave 0..4
    int lane = t & 63;
    int q = lane >> 4, rr = lane & 15;

    const short* shEf = dir ? Bf : Af;      // shared side
    const short* cdEf = dir ? Af : Bf;      // candidate side
    const float* ls = dir ? (lscT + (size_t)row * NLINES) : (lsc + (size_t)row * NLINES);

    // phase 0: stage shared-line fragments (drains during topk)
    for (int idx = t; idx < NCH * 64; idx += 320) {
        int c = idx >> 6, l = idx & 63;
        int lq = l >> 4, lr = l & 15;
        int ptS = row * 5 + min(lr, 4);
        const short* gp = shEf + ((size_t)(ptS >> 4) * NCH * 64 + lq * 16 + (ptS & 15)) * 8
                               + (size_t)c * 512;
        *(short8*)&sh_lds[c * 512 + l * 8] = *(const short8*)gp;
    }

    // phase 1a: per-wave top-10 over its 240-slice (registers + shuffles)
    float val[4];
    #pragma unroll
    for (int s = 0; s < 4; ++s) {
        int j = t + 320 * s;
        val[s] = (j < NLINES) ? ls[j] : -1e30f;
    }
    for (int sel = 0; sel < 10; ++sel) {
        float bv = -1e30f; int bi = -1;
        #pragma unroll
        for (int s = 0; s < 4; ++s) {
            int j = t + 320 * s;
            if (val[s] >= bv) { bv = val[s]; bi = j; }
        }
        #pragma unroll
        for (int o = 32; o > 0; o >>= 1) {
            float ov = __shfl_xor(bv, o);
            int oi = __shfl_xor(bi, o);
            if (ov > bv || (ov == bv && oi > bi)) { bv = ov; bi = oi; }
        }
        if (lane == 0) { wtv[w][sel] = bv; wti[w][sel] = bi; }
        if (bi >= 0 && (bi % 320) == t) val[bi / 320] = -1e30f;
    }
    __syncthreads();
    // phase 1b: single-lane 5-way merge of sorted wave lists
    if (t == 0) {
        int head[5] = {0, 0, 0, 0, 0};
        for (int sel = 0; sel < 10; ++sel) {
            float fv = -1e30f; int fi = -1, fw = 0;
            #pragma unroll
            for (int ww = 0; ww < 5; ++ww) {
                if (head[ww] < 10) {
                    float v = wtv[ww][head[ww]];
                    int ii = wti[ww][head[ww]];
                    if (v > fv || (v == fv && ii > fi)) { fv = v; fi = ii; fw = ww; }
                }
            }
            head[fw]++;
            jl[9 - sel] = fi;
        }
    }
    __syncthreads();                        // jl + sh_lds ready

    // phase 2: MFMA scores for 10 candidates (2 per wave) + NW DP
    int c1 = jl[2 * w], c2 = jl[2 * w + 1];
    int ptC = (rr < 8) ? (c1 * 5 + min(rr, 4)) : (c2 * 5 + min(rr - 8, 4));
    const short* cp = cdEf + ((size_t)(ptC >> 4) * NCH * 64 + q * 16 + (ptC & 15)) * 8;

    f32x4 acc = (f32x4){0.f, 0.f, 0.f, 0.f};
    #pragma unroll
    for (int c = 0; c < NCH; ++c) {
        short8 sh = *(const short8*)&sh_lds[c * 512 + lane * 8];
        short8 cb = *(const short8*)(cp + c * 512);
        acc = dir ? __builtin_amdgcn_mfma_f32_16x16x32_bf16(cb, sh, acc, 0, 0, 0)
                  : __builtin_amdgcn_mfma_f32_16x16x32_bf16(sh, cb, acc, 0, 0, 0);
    }
    // C layout: m = q*4+reg, n = lane&15
    #pragma unroll
    for (int reg = 0; reg < 4; ++reg) {
        int m = q * 4 + reg, n = rr;
        if (!dir) {
            if (m < 5 && n < 5) sbuf[2 * w][m * 5 + n] = acc[reg];
            if (m < 5 && n >= 8 && n < 13) sbuf[2 * w + 1][m * 5 + (n - 8)] = acc[reg];
        } else {
            if (m < 5 && n < 5) sbuf[2 * w][m * 5 + n] = acc[reg];
            if (m >= 8 && m < 13 && n < 5) sbuf[2 * w + 1][(m - 8) * 5 + n] = acc[reg];
        }
    }
    __syncthreads();

    if (t < 20) {
        int r = t >> 1, rev = t & 1;
        int i = dir ? jl[r] : row;
        int j = dir ? row : jl[r];
        float S[25];
        #pragma unroll
        for (int a = 0; a < 5; ++a) {
            float va = val1[i * NS + a];
            #pragma unroll
            for (int b = 0; b < 5; ++b) {
                float vb = val2[j * NS + b];
                S[a * 5 + b] = (va != 0.0f && vb != 0.0f) ? sbuf[r][a * 5 + b] : -1.0f;
            }
        }
        float M[25];
        #pragma unroll
        for (int x = 0; x < 5; ++x)
            #pragma unroll
            for (int y = 0; y < 5; ++y) {
                if (!dir) M[x * 5 + y] = rev ? S[x * 5 + (4 - y)] : S[x * 5 + y];
                else      M[x * 5 + y] = rev ? S[(4 - y) * 5 + x] : S[y * 5 + x];
            }
        float nwv = nw5(M);
        float* o = dir ? nw2buf : nwout;
        o[row * 20 + rev * 10 + r] = nwv;
        nwa[rev * 10 + r] = nwv;
    }
    __syncthreads();

    // phase 3: argmax over 20 (strict >, ascending = jnp.argmax first-max)
    if (t == 0) {
        float best = nwa[0]; int bi = 0;
        #pragma unroll
        for (int qq = 1; qq < 20; ++qq) {
            if (nwa[qq] > best) { best = nwa[qq]; bi = qq; }
        }
        int m = jl[bi % 10];
        if (dir) m2[row] = m; else mpre[row] = m;
    }
}

// ---------------- K4: mutual check only (tiny) ----------------------------
__global__ void mutual_kernel(const int* __restrict__ mpre, const int* __restrict__ m2,
                              float* __restrict__ out) {
    int i = blockIdx.x * 256 + threadIdx.x;
    if (i >= NLINES) return;
    int m = mpre[i];
    out[i] = (m2[m] == i) ? (float)m : -1.0f;
}

extern "C" void kernel_launch(void* const* d_in, const int* in_sizes, int n_in,
                              void* d_out, int out_size, void* d_ws, size_t ws_size,
                              hipStream_t stream) {
    const float* lseg1 = (const float*)d_in[0];
    const float* lseg2 = (const float*)d_in[1];
    const float* desc1 = (const float*)d_in[2];
    const float* desc2 = (const float*)d_in[3];
    float* out = (float*)d_out;

    float* wsf = (float*)d_ws;
    size_t off = 0;
    float* val1 = wsf + off;   off += PPAD;
    float* val2 = wsf + off;   off += PPAD;
    float* lsc = wsf + off;    off += (size_t)NLINES * NLINES;
    float* lscT = wsf + off;   off += (size_t)NLINES * NLINES;
    int* mpre = (int*)(wsf + off);  off += 1280;
    int* m2 = (int*)(wsf + off);    off += 1280;
    float* nw2buf = wsf + off; off += NLINES * 20;
    short* Aext = (short*)(wsf + off); off += (size_t)PPAD * KEXT / 2;
    short* Bext = (short*)(wsf + off); off += (size_t)PPAD * KEXT / 2;
    float* tdesc1 = wsf + off; off += (size_t)HW * DD;
    float* tdesc2 = wsf + off; off += (size_t)HW * DD;
    size_t need_full = off * sizeof(float);
    int use_t = (ws_size >= need_full) ? 1 : 0;

    if (use_t) {
        transpose_desc<<<dim3(HW / 128, DD / 32, 2), 256, 0, stream>>>(
            desc1, tdesc1, desc2, tdesc2);
    }
    samplepack_kernel<<<dim3(NGRP, 2), 1024, 0, stream>>>(
        lseg1, lseg2, tdesc1, tdesc2, desc1, desc2, Aext, Bext, val1, val2, use_t);

    score_kernel<<<dim3(NPAD / 32, NPAD / 32), 256, 0, stream>>>(Aext, Bext, val1, val2,
                                                                 lsc, lscT);

    topk_nw_kernel<<<2 * NLINES, 320, 0, stream>>>(lsc, lscT, Aext, Bext, val1, val2,
                                                   out + NLINES, nw2buf, mpre, m2);

    mutual_kernel<<<5, 256, 0, stream>>>(mpre, m2, out);
}

// Round 16
// 176.221 us; speedup vs baseline: 2.2956x; 1.0260x over previous
//
#include <hip/hip_runtime.h>
#include <hip/hip_bf16.h>

// SOLD2 line matching on MI355X.
// Inputs: line_seg1 (1200,2,2) f32, line_seg2 (1200,2,2) f32,
//         desc1 (1,128,128,128) f32, desc2 (1,128,128,128) f32
// Outputs (concat float32): matches (1200,), nw (1200,20)

#define NLINES 1200
#define NS 5
#define DD 128
#define HH 128
#define WW 128
#define HW (HH*WW)
#define IMGM1 511.0f
#define GAPC 0.1f
#define NPAD 1216          // 38*32
#define PPAD (NPAD*NS)     // 6080 padded points
#define KEXT 384           // 3-term bf16 split: [hi,lo,hi] x [hi,hi,lo]
#define NCH (KEXT/32)      // 12 k-chunks of 32
#define NGRP (PPAD/16)     // 380 16-pt groups

typedef __attribute__((ext_vector_type(8))) short short8;
typedef __attribute__((ext_vector_type(4))) float f32x4;

__device__ __forceinline__ void async_cp16(const void* g, void* l) {
    __builtin_amdgcn_global_load_lds(
        (const __attribute__((address_space(1))) void*)g,
        (__attribute__((address_space(3))) void*)l, 16, 0, 0);
}

// ------ K0: transpose desc [D][H][W] -> [H*W][D], float4 both ways --------
__global__ void transpose_desc(const float* __restrict__ in1, float* __restrict__ out1,
                               const float* __restrict__ in2, float* __restrict__ out2) {
    const float* in = blockIdx.z ? in2 : in1;
    float* out = blockIdx.z ? out2 : out1;
    __shared__ float t[32][132];
    int s0 = blockIdx.x * 128;         // HW dim
    int d0 = blockIdx.y * 32;          // D dim
    int tid = threadIdx.x;
    #pragma unroll
    for (int pass = 0; pass < 4; ++pass) {
        int idx = pass * 256 + tid;    // 0..1023 = 32 d x 32 s-chunks
        int dr = idx >> 5, si = idx & 31;
        float4 v = *(const float4*)&in[(size_t)(d0 + dr) * HW + s0 + 4 * si];
        *(float4*)&t[dr][4 * si] = v;
    }
    __syncthreads();
    #pragma unroll
    for (int pass = 0; pass < 4; ++pass) {
        int idx = pass * 256 + tid;    // 0..1023 = 128 s x 8 d-chunks
        int sr = idx >> 3, di = idx & 7;
        float4 v = { t[4 * di][sr], t[4 * di + 1][sr], t[4 * di + 2][sr], t[4 * di + 3][sr] };
        *(float4*)&out[(size_t)(s0 + sr) * DD + d0 + 4 * di] = v;
    }
}

// ------- K1: fused sample + bilinear + normalize + bf16 split + pack ------
// 1024 threads = 16 waves, one point per wave.
__global__ void samplepack_kernel(const float* __restrict__ lseg1, const float* __restrict__ lseg2,
                                  const float* __restrict__ tdesc1, const float* __restrict__ tdesc2,
                                  const float* __restrict__ desc1, const float* __restrict__ desc2,
                                  short* __restrict__ Aext, short* __restrict__ Bext,
                                  float* __restrict__ val1, float* __restrict__ val2,
                                  int use_t) {
    int side = blockIdx.y;
    const float* lseg = side ? lseg2 : lseg1;
    const float* tdesc = side ? tdesc2 : tdesc1;
    const float* desc = side ? desc2 : desc1;
    short* Ef = side ? Bext : Aext;
    float* valout = side ? val2 : val1;
    int arole = side ? 0 : 1;          // A: [hi,lo,hi]; B: [hi,hi,lo]

    __shared__ float ds[16][129];
    int g = blockIdx.x;
    int t = threadIdx.x;               // 0..1023
    int lane = t & 63, w = t >> 6;     // wave 0..15 = point index in group

    {
        int r = w;
        int pt = g * 16 + r;
        int line = pt / NS;
        int k = pt - line * NS;

        float sy = 0.f, sx = 0.f, ey = 0.f, ex = 0.f;
        if (line < NLINES) {
            sy = lseg[line * 4 + 0]; sx = lseg[line * 4 + 1];
            ey = lseg[line * 4 + 2]; ex = lseg[line * 4 + 3];
        }
        float dy = ey - sy, dx = ex - sx;
        float len = sqrtf(dy * dy + dx * dx);
        float ns = floorf(len * 0.125f);
        ns = fminf(fmaxf(ns, 2.0f), 5.0f);
        float kf = (float)k;
        float validf = (kf < ns) ? 1.0f : 0.0f;
        float py = sy + kf * (dy / (ns - 1.0f));
        float px = sx + kf * (dx / (ns - 1.0f));
        if (validf == 0.0f) { py = 0.0f; px = 0.0f; }

        float xn = 2.0f * px / IMGM1 - 1.0f;
        float yn = 2.0f * py / IMGM1 - 1.0f;
        float ix = ((xn + 1.0f) * (float)WW - 1.0f) * 0.5f;
        float iy = ((yn + 1.0f) * (float)HH - 1.0f) * 0.5f;
        float x0f = floorf(ix), y0f = floorf(iy);
        float wx = ix - x0f, wy = iy - y0f;
        int x0 = (int)x0f, y0 = (int)y0f;

        float w00 = (1.0f - wx) * (1.0f - wy);
        float w10 = wx * (1.0f - wy);
        float w01 = (1.0f - wx) * wy;
        float w11 = wx * wy;

        float v0 = 0.0f, v1 = 0.0f;
        int xs[4] = { x0, x0 + 1, x0,     x0 + 1 };
        int ys[4] = { y0, y0,     y0 + 1, y0 + 1 };
        float ws4[4] = { w00, w10, w01, w11 };
        #pragma unroll
        for (int c = 0; c < 4; ++c) {
            int xi = xs[c], yi = ys[c];
            float inb = (xi >= 0 && xi < WW && yi >= 0 && yi < HH) ? 1.0f : 0.0f;
            int xc = min(max(xi, 0), WW - 1);
            int yc = min(max(yi, 0), HH - 1);
            if (use_t) {
                int base = (yc * WW + xc) * DD;
                v0 += tdesc[base + lane] * inb * ws4[c];
                v1 += tdesc[base + 64 + lane] * inb * ws4[c];
            } else {
                int base = yc * WW + xc;
                v0 += desc[lane * HW + base] * inb * ws4[c];
                v1 += desc[(lane + 64) * HW + base] * inb * ws4[c];
            }
        }
        float ss = v0 * v0 + v1 * v1;
        #pragma unroll
        for (int o = 32; o > 0; o >>= 1) ss += __shfl_xor(ss, o);
        if (ss == 0.0f) ss = 1.0f;   // padding lines: avoid 0/0 NaN
        float nrm = sqrtf(ss);
        ds[r][lane] = v0 / nrm;
        ds[r][64 + lane] = v1 / nrm;
        if (lane == 0) valout[pt] = (line < NLINES) ? validf : 0.0f;
    }
    __syncthreads();

    if (t < 768) {                     // 12 chunks x 64 lanes
        int c = t >> 6, l = t & 63;
        int q = l >> 4, r = l & 15;
        short8 outv;
        #pragma unroll
        for (int jj = 0; jj < 8; ++jj) {
            int kext = c * 32 + q * 8 + jj;
            int term = kext >> 7, k = kext & 127;
            float x = ds[r][k];
            __hip_bfloat16 h = __float2bfloat16(x);
            short v = *(short*)&h;
            bool lo_term = arole ? (term == 1) : (term == 2);
            if (lo_term) {
                float hf = __bfloat162float(h);
                __hip_bfloat16 lw = __float2bfloat16(x - hf);
                v = *(short*)&lw;
            }
            outv[jj] = v;
        }
        *(short8*)&Ef[((size_t)(g * NCH + c) * 64 + l) * 8] = outv;
    }
}

// ---------------- K2: MFMA score GEMM + fused per-line-pair reduction -----
// R11 proven structure (51.1 us): A register double-buffer direct-global,
// B LDS-staged once per block, bounds(256,2). bounds(256,4) spills the
// accumulator (R12: 583 MB scratch writes, 6x slower).
__launch_bounds__(256, 2)
__global__ void score_kernel(const short* __restrict__ Af, const short* __restrict__ Bf,
                             const float* __restrict__ val1, const float* __restrict__ val2,
                             float* __restrict__ lsc, float* __restrict__ lscT) {
    __shared__ union {
        struct { short B[2][5120]; } st;                       // 20480 B
        struct { float dump[80 * 161]; float red[16][33]; } ep; // 53632 B
    } u;

    const int t = threadIdx.x;
    const int lane = t & 63;
    const int w = t >> 6;           // wave 0..3
    const int wm = w >> 1;          // 0..1 row half
    const int wn = w & 1;           // 0..1 col half
    const int gA0 = blockIdx.x * 10;   // first 16-pt group of A side
    const int gB0 = blockIdx.y * 10;

    const short* pa[5];
    #pragma unroll
    for (int ti = 0; ti < 5; ++ti)
        pa[ti] = Af + ((size_t)(gA0 + 5 * wm + ti) * NCH * 64 + lane) * 8;

    f32x4 acc[5][5];
    #pragma unroll
    for (int a = 0; a < 5; ++a)
        #pragma unroll
        for (int b = 0; b < 5; ++b)
            acc[a][b] = (f32x4){0.f, 0.f, 0.f, 0.f};

    // stage B chunk c into buffer b: waves 0,1 handle 5 groups each
    auto stageB = [&](int c, int b) {
        if (w < 2) {
            #pragma unroll
            for (int p = 0; p < 5; ++p) {
                int gi = w * 5 + p;
                const short* g = Bf + ((size_t)((gB0 + gi) * NCH + c) * 64 + lane) * 8;
                async_cp16(g, &u.st.B[b][gi * 512]);
            }
        }
    };

    short8 ca[5], na[5];
    stageB(0, 0);
    #pragma unroll
    for (int ti = 0; ti < 5; ++ti) ca[ti] = *(const short8*)(pa[ti]);

    #pragma unroll
    for (int c = 0; c < NCH; ++c) {
        __syncthreads();               // drains stage(c) + A-loads(c); both used now
        if (c + 1 < NCH) {
            stageB(c + 1, (c + 1) & 1);
            #pragma unroll
            for (int ti = 0; ti < 5; ++ti)
                na[ti] = *(const short8*)(pa[ti] + (c + 1) * 512);
        }
        short8 bf_[5];
        #pragma unroll
        for (int tj = 0; tj < 5; ++tj)
            bf_[tj] = *(const short8*)&u.st.B[c & 1][(5 * wn + tj) * 512 + lane * 8];
        #pragma unroll
        for (int ti = 0; ti < 5; ++ti)
            #pragma unroll
            for (int tj = 0; tj < 5; ++tj)
                acc[ti][tj] = __builtin_amdgcn_mfma_f32_16x16x32_bf16(
                    ca[ti], bf_[tj], acc[ti][tj], 0, 0, 0);
        #pragma unroll
        for (int ti = 0; ti < 5; ++ti) ca[ti] = na[ti];
    }

    const int i0l = blockIdx.x * 32;
    const int j0l = blockIdx.y * 32;
    #pragma unroll
    for (int p = 0; p < 2; ++p) {
        __syncthreads();
        if (wm == p) {
            #pragma unroll
            for (int ti = 0; ti < 5; ++ti) {
                #pragma unroll
                for (int reg = 0; reg < 4; ++reg) {
                    int rloc = 16 * ti + (lane >> 4) * 4 + reg;
                    #pragma unroll
                    for (int tj = 0; tj < 5; ++tj) {
                        int col = 80 * wn + 16 * tj + (lane & 15);
                        u.ep.dump[rloc * 161 + col] = acc[ti][tj][reg];
                    }
                }
            }
        }
        __syncthreads();
        // pass 1: reduce once per pair, write lsc (coalesced in j), park in red
        #pragma unroll
        for (int e = 0; e < 2; ++e) {
            int q = t * 2 + e;            // 0..511
            int li = q >> 5, lj = q & 31;
            int i = i0l + 16 * p + li;
            int j = j0l + lj;
            float S[5][5];
            #pragma unroll
            for (int a = 0; a < 5; ++a) {
                float va = val1[i * NS + a];   // i < NPAD always: safe
                #pragma unroll
                for (int b = 0; b < 5; ++b) {
                    float vb = val2[j * NS + b];
                    float sc = u.ep.dump[(li * 5 + a) * 161 + (lj * 5 + b)];
                    S[a][b] = (va != 0.0f && vb != 0.0f) ? sc : -1.0f;
                }
            }
            float sum1 = 0.0f, cnt1 = 0.0f;
            #pragma unroll
            for (int a = 0; a < 5; ++a) {
                float r = S[a][0];
                #pragma unroll
                for (int b = 1; b < 5; ++b) r = fmaxf(r, S[a][b]);
                float v = (r != -1.0f) ? 1.0f : 0.0f;
                sum1 += r * v; cnt1 += v;
            }
            float sum2 = 0.0f, cnt2 = 0.0f;
            #pragma unroll
            for (int b = 0; b < 5; ++b) {
                float r = S[0][b];
                #pragma unroll
                for (int a = 1; a < 5; ++a) r = fmaxf(r, S[a][b]);
                float v = (r != -1.0f) ? 1.0f : 0.0f;
                sum2 += r * v; cnt2 += v;
            }
            float res = (sum1 / cnt1 + sum2 / cnt2) * 0.5f;
            u.ep.red[li][lj] = res;
            if (i < NLINES && j < NLINES) lsc[i * NLINES + j] = res;
        }
        __syncthreads();
        // pass 2: lscT from red, coalesced in i
        #pragma unroll
        for (int e = 0; e < 2; ++e) {
            int q = t + 256 * e;          // 0..511
            int li = q & 15, lj = q >> 4;
            int i = i0l + 16 * p + li;
            int j = j0l + lj;
            if (i < NLINES && j < NLINES) lscT[j * NLINES + i] = u.ep.red[li][lj];
        }
    }
}

// ------- K3: fused top-10 + NW + per-row argmax (256 thr = 4 waves) -------
// Phase 0: stage shared-line fragments to LDS (drains during topk).
// Phase 1a: per-wave top-10 of its 320-subset (registers+shuffles, no
// barriers). Phase 1b: parallel rank selection -- 40 lanes each rank one
// candidate among all 40 by (value desc, index desc); rank<10 -> jl[9-rank].
// Exact stable-argsort (indices distinct => pairs distinct).
// Phase 2: wave w -> candidates 3w..3w+2 packed in MFMA rows 0-4/5-9/10-14
// (clamped to cand 9; duplicate writes are identical). 20-lane NW DP.
// Phase 3: per-row argmax (strict > = jnp.argmax) -> mpre/m2.
__device__ __forceinline__ float nw5(const float* M) {
    float F[6] = {0, 0, 0, 0, 0, 0};
    #pragma unroll
    for (int x = 0; x < 5; ++x) {
        float diag = F[0];
        float left = 0.0f;
        #pragma unroll
        for (int y = 1; y <= 5; ++y) {
            float up = F[y];
            float cur = fmaxf(fmaxf(left, up), diag + (M[x * 5 + y - 1] - GAPC));
            F[y] = cur; left = cur; diag = up;
        }
    }
    return F[5];
}

__global__ void topk_nw_kernel(const float* __restrict__ lsc, const float* __restrict__ lscT,
                               const short* __restrict__ Af, const short* __restrict__ Bf,
                               const float* __restrict__ val1, const float* __restrict__ val2,
                               float* __restrict__ nwout, float* __restrict__ nw2buf,
                               int* __restrict__ mpre, int* __restrict__ m2) {
    __shared__ short sh_lds[NCH * 512];     // 12 KB: shared line fragments
    __shared__ float sbuf[10][25];
    __shared__ int jl[10];
    __shared__ float wtv[4][10];
    __shared__ int wti[4][10];
    __shared__ float nwa[20];
    int rb = blockIdx.x;                    // 0..2399
    int dir = (rb >= NLINES) ? 1 : 0;
    int row = rb - dir * NLINES;
    int t = threadIdx.x;                    // 0..255
    int w = t >> 6;                         // wave 0..3
    int lane = t & 63;
    int q = lane >> 4, rr = lane & 15;

    const short* shEf = dir ? Bf : Af;      // shared side
    const short* cdEf = dir ? Af : Bf;      // candidate side
    const float* ls = dir ? (lscT + (size_t)row * NLINES) : (lsc + (size_t)row * NLINES);

    // phase 0: stage shared-line fragments (drains during topk)
    for (int idx = t; idx < NCH * 64; idx += 256) {
        int c = idx >> 6, l = idx & 63;
        int lq = l >> 4, lr = l & 15;
        int ptS = row * 5 + min(lr, 4);
        const short* gp = shEf + ((size_t)(ptS >> 4) * NCH * 64 + lq * 16 + (ptS & 15)) * 8
                               + (size_t)c * 512;
        *(short8*)&sh_lds[c * 512 + l * 8] = *(const short8*)gp;
    }

    // phase 1a: per-wave top-10 over its 320-subset (registers + shuffles)
    float val[5];
    #pragma unroll
    for (int s = 0; s < 5; ++s) {
        int j = t + 256 * s;
        val[s] = (j < NLINES) ? ls[j] : -1e30f;
    }
    for (int sel = 0; sel < 10; ++sel) {
        float bv = -1e30f; int bi = -1;
        #pragma unroll
        for (int s = 0; s < 5; ++s) {
            int j = t + 256 * s;
            if (val[s] >= bv) { bv = val[s]; bi = j; }
        }
        #pragma unroll
        for (int o = 32; o > 0; o >>= 1) {
            float ov = __shfl_xor(bv, o);
            int oi = __shfl_xor(bi, o);
            if (ov > bv || (ov == bv && oi > bi)) { bv = ov; bi = oi; }
        }
        if (lane == 0) { wtv[w][sel] = bv; wti[w][sel] = bi; }
        if (bi >= 0 && (bi & 255) == t) val[bi >> 8] = -1e30f;
    }
    __syncthreads();
    // phase 1b: parallel rank selection over the 40 candidates
    if (t < 40) {
        float v = wtv[t / 10][t % 10];
        int i = wti[t / 10][t % 10];
        int rank = 0;
        #pragma unroll
        for (int ww = 0; ww < 4; ++ww)
            #pragma unroll
            for (int ss = 0; ss < 10; ++ss) {
                float v2 = wtv[ww][ss]; int i2 = wti[ww][ss];
                if (v2 > v || (v2 == v && i2 > i)) rank++;
            }
        if (rank < 10) jl[9 - rank] = i;
    }
    __syncthreads();                        // jl + sh_lds ready

    // phase 2: MFMA scores, 3 candidates packed per wave
    int k3 = (rr < 15) ? (rr / 5) : 2;
    int ptIn = (rr < 15) ? (rr % 5) : 4;
    int cand = min(3 * w + k3, 9);
    int ptC = jl[cand] * 5 + ptIn;
    const short* cp = cdEf + ((size_t)(ptC >> 4) * NCH * 64 + q * 16 + (ptC & 15)) * 8;

    f32x4 acc = (f32x4){0.f, 0.f, 0.f, 0.f};
    #pragma unroll
    for (int c = 0; c < NCH; ++c) {
        short8 sh = *(const short8*)&sh_lds[c * 512 + lane * 8];
        short8 cb = *(const short8*)(cp + c * 512);
        acc = dir ? __builtin_amdgcn_mfma_f32_16x16x32_bf16(cb, sh, acc, 0, 0, 0)
                  : __builtin_amdgcn_mfma_f32_16x16x32_bf16(sh, cb, acc, 0, 0, 0);
    }
    // C layout: m = q*4+reg, n = lane&15.  Unpack 3 candidates per wave.
    #pragma unroll
    for (int reg = 0; reg < 4; ++reg) {
        int m = q * 4 + reg, n = rr;
        if (!dir) {
            // shared = rows (m<5), candidates packed along n
            if (m < 5 && n < 15) {
                int k = n / 5, b = n - 5 * k;
                sbuf[min(3 * w + k, 9)][m * 5 + b] = acc[reg];
            }
        } else {
            // candidates packed along m, shared = cols (n<5)
            if (n < 5 && m < 15) {
                int k = m / 5, a = m - 5 * k;
                sbuf[min(3 * w + k, 9)][a * 5 + n] = acc[reg];
            }
        }
    }
    __syncthreads();

    if (t < 20) {
        int r = t >> 1, rev = t & 1;
        int i = dir ? jl[r] : row;
        int j = dir ? row : jl[r];
        float S[25];
        #pragma unroll
        for (int a = 0; a < 5; ++a) {
            float va = val1[i * NS + a];
            #pragma unroll
            for (int b = 0; b < 5; ++b) {
                float vb = val2[j * NS + b];
                S[a * 5 + b] = (va != 0.0f && vb != 0.0f) ? sbuf[r][a * 5 + b] : -1.0f;
            }
        }
        float M[25];
        #pragma unroll
        for (int x = 0; x < 5; ++x)
            #pragma unroll
            for (int y = 0; y < 5; ++y) {
                if (!dir) M[x * 5 + y] = rev ? S[x * 5 + (4 - y)] : S[x * 5 + y];
                else      M[x * 5 + y] = rev ? S[(4 - y) * 5 + x] : S[y * 5 + x];
            }
        float nwv = nw5(M);
        float* o = dir ? nw2buf : nwout;
        o[row * 20 + rev * 10 + r] = nwv;
        nwa[rev * 10 + r] = nwv;
    }
    __syncthreads();

    // phase 3: argmax over 20 (strict >, ascending = jnp.argmax first-max)
    if (t == 0) {
        float best = nwa[0]; int bi = 0;
        #pragma unroll
        for (int qq = 1; qq < 20; ++qq) {
            if (nwa[qq] > best) { best = nwa[qq]; bi = qq; }
        }
        int m = jl[bi % 10];
        if (dir) m2[row] = m; else mpre[row] = m;
    }
}

// ---------------- K4: mutual check only (tiny) ----------------------------
__global__ void mutual_kernel(const int* __restrict__ mpre, const int* __restrict__ m2,
                              float* __restrict__ out) {
    int i = blockIdx.x * 256 + threadIdx.x;
    if (i >= NLINES) return;
    int m = mpre[i];
    out[i] = (m2[m] == i) ? (float)m : -1.0f;
}

extern "C" void kernel_launch(void* const* d_in, const int* in_sizes, int n_in,
                              void* d_out, int out_size, void* d_ws, size_t ws_size,
                              hipStream_t stream) {
    const float* lseg1 = (const float*)d_in[0];
    const float* lseg2 = (const float*)d_in[1];
    const float* desc1 = (const float*)d_in[2];
    const float* desc2 = (const float*)d_in[3];
    float* out = (float*)d_out;

    float* wsf = (float*)d_ws;
    size_t off = 0;
    float* val1 = wsf + off;   off += PPAD;
    float* val2 = wsf + off;   off += PPAD;
    float* lsc = wsf + off;    off += (size_t)NLINES * NLINES;
    float* lscT = wsf + off;   off += (size_t)NLINES * NLINES;
    int* mpre = (int*)(wsf + off);  off += 1280;
    int* m2 = (int*)(wsf + off);    off += 1280;
    float* nw2buf = wsf + off; off += NLINES * 20;
    short* Aext = (short*)(wsf + off); off += (size_t)PPAD * KEXT / 2;
    short* Bext = (short*)(wsf + off); off += (size_t)PPAD * KEXT / 2;
    float* tdesc1 = wsf + off; off += (size_t)HW * DD;
    float* tdesc2 = wsf + off; off += (size_t)HW * DD;
    size_t need_full = off * sizeof(float);
    int use_t = (ws_size >= need_full) ? 1 : 0;

    if (use_t) {
        transpose_desc<<<dim3(HW / 128, DD / 32, 2), 256, 0, stream>>>(
            desc1, tdesc1, desc2, tdesc2);
    }
    samplepack_kernel<<<dim3(NGRP, 2), 1024, 0, stream>>>(
        lseg1, lseg2, tdesc1, tdesc2, desc1, desc2, Aext, Bext, val1, val2, use_t);

    score_kernel<<<dim3(NPAD / 32, NPAD / 32), 256, 0, stream>>>(Aext, Bext, val1, val2,
                                                                 lsc, lscT);

    topk_nw_kernel<<<2 * NLINES, 256, 0, stream>>>(lsc, lscT, Aext, Bext, val1, val2,
                                                   out + NLINES, nw2buf, mpre, m2);

    mutual_kernel<<<5, 256, 0, stream>>>(mpre, m2, out);
}